// Round 9
// baseline (698.530 us; speedup 1.0000x reference)
//
#include <hip/hip_runtime.h>
#include <hip/hip_bf16.h>
#include <math.h>

#define NN 50000
#define NE 800000
#define HD 128
#define EPS_BN 1e-5f

typedef __bf16 bf16_t;
typedef bf16_t bf16x8 __attribute__((ext_vector_type(8)));
typedef bf16_t bf16x4 __attribute__((ext_vector_type(4)));
typedef float f32x4 __attribute__((ext_vector_type(4)));

// ---------------- CSR build ----------------
__global__ void count_edges(const int* __restrict__ col, int* __restrict__ counts, int E) {
    int e = blockIdx.x * 256 + threadIdx.x;
    if (e >= E) return;
    atomicAdd(&counts[col[e]], 1);
}

// scan1 + dis fused
__global__ __launch_bounds__(256) void scan1(const int* __restrict__ counts,
                                             int* __restrict__ offsets,
                                             int* __restrict__ bsum,
                                             float* __restrict__ dis, int n) {
    __shared__ int wsl[4];
    int t = threadIdx.x, lane = t & 63, w = t >> 6;
    int i = blockIdx.x * 256 + t;
    int v = (i < n) ? counts[i] : 0;
    if (i < n) dis[i] = (v > 0) ? rsqrtf((float)v) : 0.0f;
    int x = v;
    #pragma unroll
    for (int o = 1; o < 64; o <<= 1) {
        int tt = __shfl_up(x, o, 64);
        if (lane >= o) x += tt;
    }
    if (lane == 63) wsl[w] = x;
    __syncthreads();
    if (t == 0) {
        int s = 0;
        #pragma unroll
        for (int k = 0; k < 4; k++) { int tmp = wsl[k]; wsl[k] = s; s += tmp; }
        bsum[blockIdx.x] = s;
    }
    __syncthreads();
    if (i < n) offsets[i] = x - v + wsl[w];
}

__global__ __launch_bounds__(256) void scan2(int* __restrict__ bsum, int* __restrict__ offsets,
                                             int nb, int n) {
    __shared__ int wsl[4];
    int t = threadIdx.x, lane = t & 63, w = t >> 6;
    int v = (t < nb) ? bsum[t] : 0;
    int x = v;
    #pragma unroll
    for (int o = 1; o < 64; o <<= 1) {
        int tt = __shfl_up(x, o, 64);
        if (lane >= o) x += tt;
    }
    if (lane == 63) wsl[w] = x;
    __syncthreads();
    if (t == 0) {
        int s = 0;
        #pragma unroll
        for (int k = 0; k < 4; k++) { int tmp = wsl[k]; wsl[k] = s; s += tmp; }
    }
    __syncthreads();
    int excl = x - v + wsl[w];
    if (t < nb) bsum[t] = excl;
    if (t == nb - 1) offsets[n] = excl + v;
}

__global__ void scan3(int* __restrict__ offsets, const int* __restrict__ bsum, int n) {
    int i = blockIdx.x * 256 + threadIdx.x;
    if (i < n) offsets[i] += bsum[blockIdx.x];
}

__global__ void scatter_edges2(const int* __restrict__ row, const int* __restrict__ col,
                               const float* __restrict__ dis, const int* __restrict__ offsets,
                               int* __restrict__ cursor, int2* __restrict__ edges, int E) {
    int e = blockIdx.x * 256 + threadIdx.x;
    if (e >= E) return;
    int c = col[e], r = row[e];
    int pos = offsets[c] + atomicAdd(&cursor[c], 1);
    edges[pos] = make_int2(r, __float_as_int(dis[c] * dis[r]));
}

// ---------------- Graph propagation: 1 wave/node, 16 edges in flight ----------------
__global__ __launch_bounds__(256) void prop_b2(const int* __restrict__ offsets,
                                               const int2* __restrict__ edges,
                                               const bf16_t* __restrict__ in,
                                               bf16_t* __restrict__ out) {
    int wave = threadIdx.x >> 6;
    int lane = threadIdx.x & 63;
    int half = lane >> 5;
    int ch4 = (lane & 31) * 4;
    int c = blockIdx.x * 4 + wave;
    if (c >= NN) return;
    int s = offsets[c], e = offsets[c + 1];
    float a0 = 0.0f, a1 = 0.0f, a2 = 0.0f, a3 = 0.0f;
    int i = s + half;
    for (; i + 14 < e; i += 16) {
        int2 r[8];
        #pragma unroll
        for (int u = 0; u < 8; u++) r[u] = edges[i + u * 2];
        bf16x4 v[8];
        #pragma unroll
        for (int u = 0; u < 8; u++) v[u] = *(const bf16x4*)(in + ((size_t)r[u].x << 7) + ch4);
        #pragma unroll
        for (int u = 0; u < 8; u++) {
            float w = __int_as_float(r[u].y);
            a0 += w * (float)v[u][0];
            a1 += w * (float)v[u][1];
            a2 += w * (float)v[u][2];
            a3 += w * (float)v[u][3];
        }
    }
    for (; i < e; i += 2) {
        int2 r0 = edges[i];
        bf16x4 v0 = *(const bf16x4*)(in + ((size_t)r0.x << 7) + ch4);
        float w0 = __int_as_float(r0.y);
        a0 += w0 * (float)v0[0];
        a1 += w0 * (float)v0[1];
        a2 += w0 * (float)v0[2];
        a3 += w0 * (float)v0[3];
    }
    a0 += __shfl_xor(a0, 32);
    a1 += __shfl_xor(a1, 32);
    a2 += __shfl_xor(a2, 32);
    a3 += __shfl_xor(a3, 32);
    if (half == 0) {
        bf16x4 o;
        o[0] = (bf16_t)a0; o[1] = (bf16_t)a1; o[2] = (bf16_t)a2; o[3] = (bf16_t)a3;
        *(bf16x4*)(out + ((size_t)c << 7) + ch4) = o;
    }
}

// ---------------- Mega weight-pack kernel ----------------
__device__ inline void pack_frag(const float* __restrict__ W, bf16_t* __restrict__ Wp, int nkc,
                                 int lb) {
    int p = lb * 256 + threadIdx.x;
    if (p >= 8 * nkc * 64) return;
    int lane = p & 63;
    int tk = p >> 6;
    int kc = tk % nkc;
    int t = tk / nkc;
    int n = t * 16 + (lane & 15);
    int k0 = kc * 32 + (lane >> 4) * 8;
    bf16x8 f;
    #pragma unroll
    for (int j = 0; j < 8; j++) f[j] = (bf16_t)W[(size_t)(k0 + j) * 128 + n];
    *(bf16x8*)(Wp + (size_t)p * 8) = f;
}

__global__ void wcvt_all(const float* __restrict__ W_in, const float* __restrict__ Wq,
                         const float* __restrict__ Wk, const float* __restrict__ Wfc,
                         const float* __restrict__ W_out, bf16_t* __restrict__ Wp_in,
                         bf16_t* __restrict__ Wp_q, bf16_t* __restrict__ Wp_k,
                         bf16_t* __restrict__ Wp_fc, bf16_t* __restrict__ Wp_out,
                         float* __restrict__ bnsum, float* __restrict__ bnsumsq) {
    const int QSZ = HD * HD;
    const int FSZ = 8 * 20 * 64 * 8;
    int b = blockIdx.x;
    if (b < 8) { pack_frag(W_in, Wp_in, 4, b); return; }
    if (b < 16) { pack_frag(Wq, Wp_q, 4, b - 8); return; }
    if (b < 24) { pack_frag(Wq + QSZ, Wp_q + QSZ, 4, b - 16); return; }
    if (b < 32) { pack_frag(Wk, Wp_k, 4, b - 24); return; }
    if (b < 40) { pack_frag(Wk + QSZ, Wp_k + QSZ, 4, b - 32); return; }
    if (b < 80) { pack_frag(Wfc, Wp_fc, 20, b - 40); return; }
    if (b < 120) { pack_frag(Wfc + 640 * HD, Wp_fc + FSZ, 20, b - 80); return; }
    if (b < 123) {  // W_out [128][40] -> 3 tiles padded to 48
        int p = (b - 120) * 256 + threadIdx.x;
        if (p >= 3 * 4 * 64) return;
        int lane = p & 63;
        int tk = p >> 6;
        int kc = tk & 3;
        int t = tk >> 2;
        int n = t * 16 + (lane & 15);
        int k0 = kc * 32 + (lane >> 4) * 8;
        bf16x8 f;
        #pragma unroll
        for (int j = 0; j < 8; j++)
            f[j] = (n < 40) ? (bf16_t)W_out[(size_t)(k0 + j) * 40 + n] : (bf16_t)0.0f;
        *(bf16x8*)(Wp_out + (size_t)p * 8) = f;
        return;
    }
    int t = threadIdx.x;
    if (t < 128) bnsum[t] = 0.0f;
    else bnsumsq[t - 128] = 0.0f;
}

// ---------------- A-fragment loaders ----------------
__device__ inline bf16x8 loadA(const float* ap) {
    float4 a0 = *(const float4*)ap;
    float4 a1 = *(const float4*)(ap + 4);
    bf16x8 f;
    f[0] = (bf16_t)a0.x; f[1] = (bf16_t)a0.y; f[2] = (bf16_t)a0.z; f[3] = (bf16_t)a0.w;
    f[4] = (bf16_t)a1.x; f[5] = (bf16_t)a1.y; f[6] = (bf16_t)a1.z; f[7] = (bf16_t)a1.w;
    return f;
}
__device__ inline bf16x8 loadA(const bf16_t* ap) { return *(const bf16x8*)ap; }

// ---------------- MFMA GEMM (K=128): norm / den+scale / bn-stats / zero-buf fusion ----------------
template <typename T, bool NORM>
__global__ __launch_bounds__(256) void gemm128s(const T* __restrict__ A,
                                                const bf16_t* __restrict__ Wp,
                                                const float* __restrict__ bias,
                                                const float* __restrict__ ksum_p,
                                                float* __restrict__ den_out,
                                                float* __restrict__ sums,
                                                float* __restrict__ sumsq,
                                                float* __restrict__ zero_buf, int zero_len,
                                                float* __restrict__ out,
                                                bf16_t* __restrict__ outb, int N) {
    __shared__ float lsum[128], lsq[128];
    int tid = threadIdx.x;
    if (zero_buf && blockIdx.x < 17) {  // zero kvs+ksum+vsum for the next kernel
        int base = (blockIdx.x * 256 + tid) * 4;
        if (base < zero_len) *(float4*)(zero_buf + base) = make_float4(0.f, 0.f, 0.f, 0.f);
    }
    int wave = tid >> 6;
    int lane = tid & 63;
    int quad = lane >> 4;
    int l16 = lane & 15;
    int m0 = blockIdx.x * 64 + wave * 16;
    int arow = m0 + l16;

    f32x4 acc[8] = {};
    #pragma unroll
    for (int kc = 0; kc < 4; kc++) {
        bf16x8 afrag = {};
        if (arow < N) afrag = loadA(A + ((size_t)arow << 7) + kc * 32 + quad * 8);
        bf16x8 bfr[8];
        #pragma unroll
        for (int t = 0; t < 8; t++)
            bfr[t] = *(const bf16x8*)(Wp + (size_t)(((t * 4 + kc) * 64) + lane) * 8);
        #pragma unroll
        for (int t = 0; t < 8; t++)
            acc[t] = __builtin_amdgcn_mfma_f32_16x16x32_bf16(afrag, bfr[t], acc[t], 0, 0, 0);
    }
    float vals[8][4];
    #pragma unroll
    for (int t = 0; t < 8; t++) {
        float b = bias ? bias[t * 16 + l16] : 0.0f;
        #pragma unroll
        for (int r = 0; r < 4; r++) vals[t][r] = acc[t][r] + b;
    }
    if (NORM) {
        #pragma unroll
        for (int r = 0; r < 4; r++) {
            float p = 0.0f;
            #pragma unroll
            for (int t = 0; t < 8; t++) p += vals[t][r] * vals[t][r];
            p += __shfl_xor(p, 1);
            p += __shfl_xor(p, 2);
            p += __shfl_xor(p, 4);
            p += __shfl_xor(p, 8);
            float inv = rsqrtf(p);
            #pragma unroll
            for (int t = 0; t < 8; t++) vals[t][r] *= inv;
        }
    }
    if (ksum_p) {  // fused den = qn . ksum + N; scale row by 1/den
        float kv[8];
        #pragma unroll
        for (int t = 0; t < 8; t++) kv[t] = ksum_p[t * 16 + l16];
        #pragma unroll
        for (int r = 0; r < 4; r++) {
            float dp = 0.0f;
            #pragma unroll
            for (int t = 0; t < 8; t++) dp += vals[t][r] * kv[t];
            dp += __shfl_xor(dp, 1);
            dp += __shfl_xor(dp, 2);
            dp += __shfl_xor(dp, 4);
            dp += __shfl_xor(dp, 8);
            float dv = dp + (float)NN;
            int rr = m0 + quad * 4 + r;
            if (l16 == 0 && rr < N) den_out[rr] = dv;
            float dinv = 1.0f / dv;
            #pragma unroll
            for (int t = 0; t < 8; t++) vals[t][r] *= dinv;
        }
    }
    #pragma unroll
    for (int r = 0; r < 4; r++) {
        int rr = m0 + quad * 4 + r;
        if (rr >= N) continue;
        #pragma unroll
        for (int t = 0; t < 8; t++) {
            int c = t * 16 + l16;
            float v = vals[t][r];
            if (out) out[((size_t)rr << 7) + c] = v;
            if (outb) outb[((size_t)rr << 7) + c] = (bf16_t)v;
        }
    }
    if (sums) {  // fused BN stats
        if (tid < 128) { lsum[tid] = 0.0f; lsq[tid] = 0.0f; }
        __syncthreads();
        float sp[8] = {}, qp[8] = {};
        #pragma unroll
        for (int r = 0; r < 4; r++) {
            int rr = m0 + quad * 4 + r;
            if (rr >= N) continue;
            #pragma unroll
            for (int t = 0; t < 8; t++) {
                float v = vals[t][r];
                sp[t] += v;
                qp[t] += v * v;
            }
        }
        #pragma unroll
        for (int t = 0; t < 8; t++) {
            sp[t] += __shfl_xor(sp[t], 16);
            sp[t] += __shfl_xor(sp[t], 32);
            qp[t] += __shfl_xor(qp[t], 16);
            qp[t] += __shfl_xor(qp[t], 32);
        }
        if (quad == 0) {
            #pragma unroll
            for (int t = 0; t < 8; t++) {
                atomicAdd(&lsum[t * 16 + l16], sp[t]);
                atomicAdd(&lsq[t * 16 + l16], qp[t]);
            }
        }
        __syncthreads();
        if (tid < 128) {
            atomicAdd(&sums[tid], lsum[tid]);
            atomicAdd(&sumsq[tid], lsq[tid]);
        }
    }
}

// ---------------- fc GEMM: single 640-K loop, 2 m-tiles/wave, fused BN stats ----------------
__global__ __launch_bounds__(256, 1) void gemm_fc(
    const bf16_t* __restrict__ qn, const bf16_t* __restrict__ s1, const bf16_t* __restrict__ s2,
    const bf16_t* __restrict__ s3, const bf16_t* __restrict__ s4,
    const bf16_t* __restrict__ WpM1, const bf16_t* __restrict__ Wp,
    const float* __restrict__ bvec, const float* __restrict__ bfc,
    const float* __restrict__ den, const bf16_t* __restrict__ resb,
    float* __restrict__ sums, float* __restrict__ sumsq,
    bf16_t* __restrict__ outb, int N) {
    __shared__ float lsum[128], lsq[128];
    const bf16_t* srcs[5] = {qn, s1, s2, s3, s4};
    int tid = threadIdx.x;
    int wave = tid >> 6;
    int lane = tid & 63;
    int quad = lane >> 4;
    int l16 = lane & 15;
    int m0 = blockIdx.x * 128 + wave * 32;  // 2 m-tiles per wave

    f32x4 acc[2][8] = {};
    #pragma unroll
    for (int kc = 0; kc < 20; kc++) {
        int s = kc >> 2;
        int klocal = (kc & 3) * 32;
        bf16x8 bfr[8];
        #pragma unroll
        for (int t = 0; t < 8; t++) {
            const bf16_t* bp = (kc < 4) ? WpM1 + (size_t)(((t * 4 + kc) * 64) + lane) * 8
                                        : Wp + (size_t)(((t * 20 + kc) * 64) + lane) * 8;
            bfr[t] = *(const bf16x8*)bp;
        }
        bf16x8 af[2] = {};
        #pragma unroll
        for (int m = 0; m < 2; m++) {
            int arow = m0 + m * 16 + l16;
            if (arow < N)
                af[m] = *(const bf16x8*)(srcs[s] + ((size_t)arow << 7) + klocal + quad * 8);
        }
        #pragma unroll
        for (int t = 0; t < 8; t++) {
            #pragma unroll
            for (int m = 0; m < 2; m++)
                acc[m][t] = __builtin_amdgcn_mfma_f32_16x16x32_bf16(af[m], bfr[t], acc[m][t],
                                                                    0, 0, 0);
        }
    }
    float bv[8], bf[8];
    #pragma unroll
    for (int t = 0; t < 8; t++) {
        bv[t] = bvec[t * 16 + l16];
        bf[t] = bfc[t * 16 + l16];
    }
    if (tid < 128) { lsum[tid] = 0.0f; lsq[tid] = 0.0f; }
    __syncthreads();
    float sp[8] = {}, qp[8] = {};
    #pragma unroll
    for (int m = 0; m < 2; m++) {
        #pragma unroll
        for (int r = 0; r < 4; r++) {
            int rr = m0 + m * 16 + quad * 4 + r;
            if (rr >= N) continue;
            float dinv = 1.0f / den[rr];
            #pragma unroll
            for (int t = 0; t < 8; t++) {
                int c = t * 16 + l16;
                float v = acc[m][t][r] + dinv * bv[t] + bf[t] +
                          (float)resb[((size_t)rr << 7) + c];
                outb[((size_t)rr << 7) + c] = (bf16_t)v;
                sp[t] += v;
                qp[t] += v * v;
            }
        }
    }
    #pragma unroll
    for (int t = 0; t < 8; t++) {
        sp[t] += __shfl_xor(sp[t], 16);
        sp[t] += __shfl_xor(sp[t], 32);
        qp[t] += __shfl_xor(qp[t], 16);
        qp[t] += __shfl_xor(qp[t], 32);
    }
    if (quad == 0) {
        #pragma unroll
        for (int t = 0; t < 8; t++) {
            atomicAdd(&lsum[t * 16 + l16], sp[t]);
            atomicAdd(&lsq[t * 16 + l16], qp[t]);
        }
    }
    __syncthreads();
    if (tid < 128) {
        atomicAdd(&sums[tid], lsum[tid]);
        atomicAdd(&sumsq[tid], lsq[tid]);
    }
}

// ---------------- out GEMM via MFMA ----------------
__global__ __launch_bounds__(256) void out_mfma(const bf16_t* __restrict__ hb,
                                                const bf16_t* __restrict__ Wp,
                                                const float* __restrict__ bias,
                                                float* __restrict__ out, int N) {
    int wave = threadIdx.x >> 6;
    int lane = threadIdx.x & 63;
    int quad = lane >> 4;
    int l16 = lane & 15;
    int m0 = blockIdx.x * 64 + wave * 16;
    int arow = m0 + l16;

    f32x4 acc[3] = {};
    #pragma unroll
    for (int kc = 0; kc < 4; kc++) {
        bf16x8 afrag = {};
        if (arow < N) afrag = *(const bf16x8*)(hb + ((size_t)arow << 7) + kc * 32 + quad * 8);
        #pragma unroll
        for (int t = 0; t < 3; t++) {
            const bf16_t* bp = Wp + (size_t)(((t * 4 + kc) * 64) + lane) * 8;
            acc[t] = __builtin_amdgcn_mfma_f32_16x16x32_bf16(afrag, *(const bf16x8*)bp, acc[t],
                                                             0, 0, 0);
        }
    }
    #pragma unroll
    for (int r = 0; r < 4; r++) {
        int rr = m0 + quad * 4 + r;
        if (rr >= N) continue;
        #pragma unroll
        for (int t = 0; t < 3; t++) {
            int c = t * 16 + l16;
            if (c < 40) out[(size_t)rr * 40 + c] = acc[t][r] + bias[c];
        }
    }
}

// ---------------- kvs via MFMA ----------------
__global__ __launch_bounds__(256) void kvs_mfma(const bf16_t* __restrict__ kn,
                                                const bf16_t* __restrict__ v,
                                                float* __restrict__ kvs,
                                                float* __restrict__ ksum,
                                                float* __restrict__ vsum, int N) {
    __shared__ bf16_t Lk[32][132];
    __shared__ bf16_t Lv[32][132];
    __shared__ float lred[256];
    int t = threadIdx.x;
    int wave = t >> 6, lane = t & 63, quad = lane >> 4, l16 = lane & 15;
    int tr = t >> 4, tc = (t & 15) * 8;
    int mbase = wave * 32;
    f32x4 acc[2][8] = {};
    float ks[8] = {}, vs[8] = {};
    for (int base = blockIdx.x * 32; base < N; base += gridDim.x * 32) {
        __syncthreads();
        #pragma unroll
        for (int hh = 0; hh < 2; hh++) {
            int r = hh * 16 + tr;
            int rowi = base + r;
            bf16x8 ck = {}, cv = {};
            if (rowi < N) {
                ck = *(const bf16x8*)(kn + ((size_t)rowi << 7) + tc);
                cv = *(const bf16x8*)(v + ((size_t)rowi << 7) + tc);
            }
            bf16x4 klo, khi, vlo, vhi;
            #pragma unroll
            for (int j = 0; j < 4; j++) {
                klo[j] = ck[j]; khi[j] = ck[j + 4];
                vlo[j] = cv[j]; vhi[j] = cv[j + 4];
                ks[j] += (float)ck[j]; ks[j + 4] += (float)ck[j + 4];
                vs[j] += (float)cv[j]; vs[j + 4] += (float)cv[j + 4];
            }
            *(bf16x4*)&Lk[r][tc] = klo;
            *(bf16x4*)&Lk[r][tc + 4] = khi;
            *(bf16x4*)&Lv[r][tc] = vlo;
            *(bf16x4*)&Lv[r][tc + 4] = vhi;
        }
        __syncthreads();
        bf16x8 af[2], bfr[8];
        #pragma unroll
        for (int mt = 0; mt < 2; mt++)
            #pragma unroll
            for (int j = 0; j < 8; j++) af[mt][j] = Lk[quad * 8 + j][mbase + mt * 16 + l16];
        #pragma unroll
        for (int tt = 0; tt < 8; tt++)
            #pragma unroll
            for (int j = 0; j < 8; j++) bfr[tt][j] = Lv[quad * 8 + j][tt * 16 + l16];
        #pragma unroll
        for (int mt = 0; mt < 2; mt++)
            #pragma unroll
            for (int tt = 0; tt < 8; tt++)
                acc[mt][tt] = __builtin_amdgcn_mfma_f32_16x16x32_bf16(af[mt], bfr[tt],
                                                                      acc[mt][tt], 0, 0, 0);
    }
    #pragma unroll
    for (int mt = 0; mt < 2; mt++)
        #pragma unroll
        for (int tt = 0; tt < 8; tt++)
            #pragma unroll
            for (int r = 0; r < 4; r++) {
                int m = mbase + mt * 16 + quad * 4 + r;
                int d = tt * 16 + l16;
                atomicAdd(&kvs[m * HD + d], acc[mt][tt][r]);
            }
    lred[t] = 0.0f;
    __syncthreads();
    #pragma unroll
    for (int j = 0; j < 8; j++) {
        atomicAdd(&lred[tc + j], ks[j]);
        atomicAdd(&lred[128 + tc + j], vs[j]);
    }
    __syncthreads();
    if (t < 128) {
        atomicAdd(&ksum[t], lred[t]);
        atomicAdd(&vsum[t], lred[t + 128]);
    }
}

// ---------------- M1 = kvs @ W0 (frag-packed), bvec = vsum @ W0, zero BN stats ----------------
__global__ void m1_pack(const float* __restrict__ kvs, const float* __restrict__ W0,
                        const float* __restrict__ vsum, bf16_t* __restrict__ WpM1,
                        float* __restrict__ bvec, float* __restrict__ bnsum,
                        float* __restrict__ bnsumsq) {
    if (blockIdx.x == 64) {
        int t = threadIdx.x;
        if (t < 128) {
            bnsum[t] = 0.0f;
            float acc = 0.0f;
            for (int d = 0; d < 128; d++) acc += vsum[d] * W0[d * 128 + t];
            bvec[t] = acc;
        } else {
            bnsumsq[t - 128] = 0.0f;
        }
        return;
    }
    int idx = blockIdx.x * 256 + threadIdx.x;
    int m = idx >> 7;
    int c = idx & 127;
    float acc = 0.0f;
    for (int d = 0; d < 128; d += 4) {
        float4 k4 = *(const float4*)(kvs + m * 128 + d);
        acc += k4.x * W0[(d + 0) * 128 + c] + k4.y * W0[(d + 1) * 128 + c] +
               k4.z * W0[(d + 2) * 128 + c] + k4.w * W0[(d + 3) * 128 + c];
    }
    int t = c >> 4, l16 = c & 15, kc = m >> 5, quad = (m >> 3) & 3, j = m & 7;
    int lane = quad * 16 + l16;
    WpM1[(size_t)(((t * 4 + kc) * 64) + lane) * 8 + j] = (bf16_t)acc;
}

// ---------------- BN apply (finalize fused per block) ----------------
__global__ void bn_apply2(const bf16_t* __restrict__ z, bf16_t* __restrict__ hb,
                          const float* __restrict__ sums, const float* __restrict__ sumsq,
                          const float* __restrict__ g, const float* __restrict__ bb, int n4) {
    __shared__ float sc[128], sh[128];
    int t = threadIdx.x;
    if (t < 128) {
        float m = sums[t] / (float)NN;
        float var = sumsq[t] / (float)NN - m * m;
        float s = g[t] * rsqrtf(var + EPS_BN);
        sc[t] = s;
        sh[t] = bb[t] - m * s;
    }
    __syncthreads();
    int i = blockIdx.x * 256 + t;
    if (i >= n4) return;
    int c4 = (i & 31) * 4;
    bf16x4 zv = *(const bf16x4*)(z + (size_t)i * 4);
    bf16x4 o;
    #pragma unroll
    for (int j = 0; j < 4; j++)
        o[j] = (bf16_t)fmaxf((float)zv[j] * sc[c4 + j] + sh[c4 + j], 0.0f);
    *(bf16x4*)(hb + (size_t)i * 4) = o;
}

extern "C" void kernel_launch(void* const* d_in, const int* in_sizes, int n_in,
                              void* d_out, int out_size, void* d_ws, size_t ws_size,
                              hipStream_t stream) {
    const float* x = (const float*)d_in[0];
    const int* eidx = (const int*)d_in[1];
    const float* W_in = (const float*)d_in[2];
    const float* b_in = (const float*)d_in[3];
    const float* Wq = (const float*)d_in[4];
    const float* bq = (const float*)d_in[5];
    const float* Wk = (const float*)d_in[6];
    const float* bk = (const float*)d_in[7];
    const float* Wfc = (const float*)d_in[8];
    const float* bfc = (const float*)d_in[9];
    const float* W_out = (const float*)d_in[10];
    const float* b_out = (const float*)d_in[11];
    const float* bn_g = (const float*)d_in[12];
    const float* bn_b = (const float*)d_in[13];
    float* out = (float*)d_out;

    const int N = NN, E = NE;
    const int* rowp = eidx;
    const int* colp = eidx + E;

    char* ws = (char*)d_ws;
    size_t off = 0;
    auto nxt = [&](size_t bytes) -> void* {
        void* p = ws + off;
        off += (bytes + 255) & ~(size_t)255;
        return p;
    };
    int* counts = (int*)nxt((size_t)N * 4);
    int* cursor = (int*)nxt((size_t)N * 4);  // adjacent to counts: one memset covers both
    int* offsets = (int*)nxt((size_t)(N + 1) * 4);
    int* bsum = (int*)nxt(1024);
    int2* edges = (int2*)nxt((size_t)E * 8);
    float* dis = (float*)nxt((size_t)N * 4);
    float* den = (float*)nxt((size_t)N * 4);
    float* kvs = (float*)nxt((size_t)HD * HD * 4);  // + ksum + vsum contiguous
    float* ksum = (float*)nxt((size_t)HD * 4);
    float* vsum = (float*)nxt((size_t)HD * 4);
    float* bnsum = (float*)nxt((size_t)HD * 4);
    float* bnsumsq = (float*)nxt((size_t)HD * 4);
    float* bvec = (float*)nxt((size_t)HD * 4);
    // bf16 activations
    bf16_t* zb = (bf16_t*)nxt((size_t)N * HD * 2);
    bf16_t* hb = (bf16_t*)nxt((size_t)N * HD * 2);
    bf16_t* p1b = (bf16_t*)nxt((size_t)N * HD * 2);
    bf16_t* p2b = (bf16_t*)nxt((size_t)N * HD * 2);
    bf16_t* p3b = (bf16_t*)nxt((size_t)N * HD * 2);
    bf16_t* knb = (bf16_t*)nxt((size_t)N * HD * 2);
    bf16_t* qnb = (bf16_t*)nxt((size_t)N * HD * 2);
    // fragment-packed bf16 weights
    bf16_t* Wp_in = (bf16_t*)nxt((size_t)8 * 4 * 64 * 8 * 2);
    bf16_t* Wp_q = (bf16_t*)nxt((size_t)2 * 8 * 4 * 64 * 8 * 2);
    bf16_t* Wp_k = (bf16_t*)nxt((size_t)2 * 8 * 4 * 64 * 8 * 2);
    bf16_t* Wp_fc = (bf16_t*)nxt((size_t)2 * 8 * 20 * 64 * 8 * 2);
    bf16_t* WpM1 = (bf16_t*)nxt((size_t)8 * 4 * 64 * 8 * 2);
    bf16_t* Wp_out = (bf16_t*)nxt((size_t)3 * 4 * 64 * 8 * 2);

    const int GB = (N + 63) / 64;
    const int GB2 = (N + 127) / 128;
    const int QSZ = HD * HD;
    const int FSZ = 8 * 20 * 64 * 8;
    const int NB = (N + 255) / 256;

    // ---- CSR build ----
    hipMemsetAsync(counts, 0, (size_t)2 * ((N * 4 + 255) & ~255), stream);
    count_edges<<<(E + 255) / 256, 256, 0, stream>>>(colp, counts, E);
    scan1<<<NB, 256, 0, stream>>>(counts, offsets, bsum, dis, N);
    scan2<<<1, 256, 0, stream>>>(bsum, offsets, NB, N);
    scan3<<<NB, 256, 0, stream>>>(offsets, bsum, N);
    scatter_edges2<<<(E + 255) / 256, 256, 0, stream>>>(rowp, colp, dis, offsets, cursor,
                                                        edges, E);

    // ---- all weight packing + zero BN stats (one launch) ----
    wcvt_all<<<124, 256, 0, stream>>>(W_in, Wq, Wk, Wfc, W_out, Wp_in, Wp_q, Wp_k, Wp_fc,
                                      Wp_out, bnsum, bnsumsq);

    // ---- input layer (fused BN stats) ----
    gemm128s<float, false><<<GB, 256, 0, stream>>>(x, Wp_in, b_in, nullptr, nullptr, bnsum,
                                                   bnsumsq, nullptr, 0, nullptr, zb, N);
    bn_apply2<<<(N * 32 + 255) / 256, 256, 0, stream>>>(zb, hb, bnsum, bnsumsq, bn_g, bn_b,
                                                        N * 32);

    for (int i = 0; i < 2; i++) {
        const float* bq_i = bq + (size_t)i * HD;
        const float* bk_i = bk + (size_t)i * HD;
        const float* bfc_i = bfc + (size_t)i * HD;
        const float* Wfc_i = Wfc + (size_t)i * 640 * HD;  // rows 0..127 = W0
        bf16_t* Wp_q_i = Wp_q + (size_t)i * QSZ;
        bf16_t* Wp_k_i = Wp_k + (size_t)i * QSZ;
        bf16_t* Wp_fc_i = Wp_fc + (size_t)i * FSZ;

        // K-hop diffusion (bf16)
        prop_b2<<<(N + 3) / 4, 256, 0, stream>>>(offsets, edges, hb, p1b);
        prop_b2<<<(N + 3) / 4, 256, 0, stream>>>(offsets, edges, p1b, p2b);
        prop_b2<<<(N + 3) / 4, 256, 0, stream>>>(offsets, edges, p2b, p3b);

        // attention: k-gemm (also zeroes kvs+ksum+vsum), kvs, q-gemm (fused den)
        gemm128s<bf16_t, true><<<GB, 256, 0, stream>>>(hb, Wp_k_i, bk_i, nullptr, nullptr,
                                                       nullptr, nullptr, kvs, HD * HD + 2 * HD,
                                                       nullptr, knb, N);
        kvs_mfma<<<256, 256, 0, stream>>>(knb, hb, kvs, ksum, vsum, N);
        gemm128s<bf16_t, true><<<GB, 256, 0, stream>>>(hb, Wp_q_i, bq_i, ksum, den, nullptr,
                                                       nullptr, nullptr, 0, nullptr, qnb, N);
        m1_pack<<<65, 256, 0, stream>>>(kvs, Wfc_i, vsum, WpM1, bvec, bnsum, bnsumsq);

        // z = qn@M1 + dinv*bvec + [h,p1,p2,p3]@W[128:] + bfc + hb  (fused BN stats)
        gemm_fc<<<GB2, 256, 0, stream>>>(qnb, hb, p1b, p2b, p3b, WpM1, Wp_fc_i, bvec, bfc_i,
                                         den, hb, bnsum, bnsumsq, zb, N);
        bn_apply2<<<(N * 32 + 255) / 256, 256, 0, stream>>>(zb, hb, bnsum, bnsumsq,
                                                            bn_g + (size_t)(i + 1) * HD,
                                                            bn_b + (size_t)(i + 1) * HD,
                                                            N * 32);
    }

    out_mfma<<<GB, 256, 0, stream>>>(hb, Wp_out, b_out, out, N);
}

// Round 10
// 643.542 us; speedup vs baseline: 1.0854x; 1.0854x over previous
//
#include <hip/hip_runtime.h>
#include <hip/hip_bf16.h>
#include <math.h>

#define NN 50000
#define NE 800000
#define HD 128
#define EPS_BN 1e-5f

typedef __bf16 bf16_t;
typedef bf16_t bf16x8 __attribute__((ext_vector_type(8)));
typedef bf16_t bf16x4 __attribute__((ext_vector_type(4)));
typedef float f32x4 __attribute__((ext_vector_type(4)));

// ---------------- CSR build ----------------
__global__ void count_edges(const int* __restrict__ col, int* __restrict__ counts, int E) {
    int e = blockIdx.x * 256 + threadIdx.x;
    if (e >= E) return;
    atomicAdd(&counts[col[e]], 1);
}

// scan1 + dis fused
__global__ __launch_bounds__(256) void scan1(const int* __restrict__ counts,
                                             int* __restrict__ offsets,
                                             int* __restrict__ bsum,
                                             float* __restrict__ dis, int n) {
    __shared__ int wsl[4];
    int t = threadIdx.x, lane = t & 63, w = t >> 6;
    int i = blockIdx.x * 256 + t;
    int v = (i < n) ? counts[i] : 0;
    if (i < n) dis[i] = (v > 0) ? rsqrtf((float)v) : 0.0f;
    int x = v;
    #pragma unroll
    for (int o = 1; o < 64; o <<= 1) {
        int tt = __shfl_up(x, o, 64);
        if (lane >= o) x += tt;
    }
    if (lane == 63) wsl[w] = x;
    __syncthreads();
    if (t == 0) {
        int s = 0;
        #pragma unroll
        for (int k = 0; k < 4; k++) { int tmp = wsl[k]; wsl[k] = s; s += tmp; }
        bsum[blockIdx.x] = s;
    }
    __syncthreads();
    if (i < n) offsets[i] = x - v + wsl[w];
}

__global__ __launch_bounds__(256) void scan2(int* __restrict__ bsum, int* __restrict__ offsets,
                                             int nb, int n) {
    __shared__ int wsl[4];
    int t = threadIdx.x, lane = t & 63, w = t >> 6;
    int v = (t < nb) ? bsum[t] : 0;
    int x = v;
    #pragma unroll
    for (int o = 1; o < 64; o <<= 1) {
        int tt = __shfl_up(x, o, 64);
        if (lane >= o) x += tt;
    }
    if (lane == 63) wsl[w] = x;
    __syncthreads();
    if (t == 0) {
        int s = 0;
        #pragma unroll
        for (int k = 0; k < 4; k++) { int tmp = wsl[k]; wsl[k] = s; s += tmp; }
    }
    __syncthreads();
    int excl = x - v + wsl[w];
    if (t < nb) bsum[t] = excl;
    if (t == nb - 1) offsets[n] = excl + v;
}

__global__ void scan3(int* __restrict__ offsets, const int* __restrict__ bsum, int n) {
    int i = blockIdx.x * 256 + threadIdx.x;
    if (i < n) offsets[i] += bsum[blockIdx.x];
}

__global__ void scatter_edges2(const int* __restrict__ row, const int* __restrict__ col,
                               const float* __restrict__ dis, const int* __restrict__ offsets,
                               int* __restrict__ cursor, int2* __restrict__ edges, int E) {
    int e = blockIdx.x * 256 + threadIdx.x;
    if (e >= E) return;
    int c = col[e], r = row[e];
    int pos = offsets[c] + atomicAdd(&cursor[c], 1);
    edges[pos] = make_int2(r, __float_as_int(dis[c] * dis[r]));
}

// ---------------- Graph propagation: 1 wave/node, 4-edge batch + tail (round-8 body) ----------------
__global__ __launch_bounds__(256) void prop_b2(const int* __restrict__ offsets,
                                               const int2* __restrict__ edges,
                                               const bf16_t* __restrict__ in,
                                               bf16_t* __restrict__ out) {
    int wave = threadIdx.x >> 6;
    int lane = threadIdx.x & 63;
    int half = lane >> 5;
    int ch4 = (lane & 31) * 4;
    int c = blockIdx.x * 4 + wave;
    if (c >= NN) return;
    int s = offsets[c], e = offsets[c + 1];
    float a0 = 0.0f, a1 = 0.0f, a2 = 0.0f, a3 = 0.0f;
    int i = s + half;
    for (; i + 6 < e; i += 8) {
        int2 r0 = edges[i], r1 = edges[i + 2], r2 = edges[i + 4], r3 = edges[i + 6];
        bf16x4 v0 = *(const bf16x4*)(in + ((size_t)r0.x << 7) + ch4);
        bf16x4 v1 = *(const bf16x4*)(in + ((size_t)r1.x << 7) + ch4);
        bf16x4 v2 = *(const bf16x4*)(in + ((size_t)r2.x << 7) + ch4);
        bf16x4 v3 = *(const bf16x4*)(in + ((size_t)r3.x << 7) + ch4);
        float w0 = __int_as_float(r0.y), w1 = __int_as_float(r1.y);
        float w2 = __int_as_float(r2.y), w3 = __int_as_float(r3.y);
        a0 += w0 * (float)v0[0] + w1 * (float)v1[0] + w2 * (float)v2[0] + w3 * (float)v3[0];
        a1 += w0 * (float)v0[1] + w1 * (float)v1[1] + w2 * (float)v2[1] + w3 * (float)v3[1];
        a2 += w0 * (float)v0[2] + w1 * (float)v1[2] + w2 * (float)v2[2] + w3 * (float)v3[2];
        a3 += w0 * (float)v0[3] + w1 * (float)v1[3] + w2 * (float)v2[3] + w3 * (float)v3[3];
    }
    for (; i < e; i += 2) {
        int2 r0 = edges[i];
        bf16x4 v0 = *(const bf16x4*)(in + ((size_t)r0.x << 7) + ch4);
        float w0 = __int_as_float(r0.y);
        a0 += w0 * (float)v0[0];
        a1 += w0 * (float)v0[1];
        a2 += w0 * (float)v0[2];
        a3 += w0 * (float)v0[3];
    }
    a0 += __shfl_xor(a0, 32);
    a1 += __shfl_xor(a1, 32);
    a2 += __shfl_xor(a2, 32);
    a3 += __shfl_xor(a3, 32);
    if (half == 0) {
        bf16x4 o;
        o[0] = (bf16_t)a0; o[1] = (bf16_t)a1; o[2] = (bf16_t)a2; o[3] = (bf16_t)a3;
        *(bf16x4*)(out + ((size_t)c << 7) + ch4) = o;
    }
}

// ---------------- Mega weight-pack kernel ----------------
__device__ inline void pack_frag(const float* __restrict__ W, bf16_t* __restrict__ Wp, int nkc,
                                 int lb) {
    int p = lb * 256 + threadIdx.x;
    if (p >= 8 * nkc * 64) return;
    int lane = p & 63;
    int tk = p >> 6;
    int kc = tk % nkc;
    int t = tk / nkc;
    int n = t * 16 + (lane & 15);
    int k0 = kc * 32 + (lane >> 4) * 8;
    bf16x8 f;
    #pragma unroll
    for (int j = 0; j < 8; j++) f[j] = (bf16_t)W[(size_t)(k0 + j) * 128 + n];
    *(bf16x8*)(Wp + (size_t)p * 8) = f;
}

__global__ void wcvt_all(const float* __restrict__ W_in, const float* __restrict__ Wq,
                         const float* __restrict__ Wk, const float* __restrict__ Wfc,
                         const float* __restrict__ W_out, bf16_t* __restrict__ Wp_in,
                         bf16_t* __restrict__ Wp_q, bf16_t* __restrict__ Wp_k,
                         bf16_t* __restrict__ Wp_fc, bf16_t* __restrict__ Wp_out,
                         float* __restrict__ bnsum, float* __restrict__ bnsumsq) {
    const int QSZ = HD * HD;
    const int FSZ = 8 * 20 * 64 * 8;
    int b = blockIdx.x;
    if (b < 8) { pack_frag(W_in, Wp_in, 4, b); return; }
    if (b < 16) { pack_frag(Wq, Wp_q, 4, b - 8); return; }
    if (b < 24) { pack_frag(Wq + QSZ, Wp_q + QSZ, 4, b - 16); return; }
    if (b < 32) { pack_frag(Wk, Wp_k, 4, b - 24); return; }
    if (b < 40) { pack_frag(Wk + QSZ, Wp_k + QSZ, 4, b - 32); return; }
    if (b < 80) { pack_frag(Wfc, Wp_fc, 20, b - 40); return; }
    if (b < 120) { pack_frag(Wfc + 640 * HD, Wp_fc + FSZ, 20, b - 80); return; }
    if (b < 123) {  // W_out [128][40] -> 3 tiles padded to 48
        int p = (b - 120) * 256 + threadIdx.x;
        if (p >= 3 * 4 * 64) return;
        int lane = p & 63;
        int tk = p >> 6;
        int kc = tk & 3;
        int t = tk >> 2;
        int n = t * 16 + (lane & 15);
        int k0 = kc * 32 + (lane >> 4) * 8;
        bf16x8 f;
        #pragma unroll
        for (int j = 0; j < 8; j++)
            f[j] = (n < 40) ? (bf16_t)W_out[(size_t)(k0 + j) * 40 + n] : (bf16_t)0.0f;
        *(bf16x8*)(Wp_out + (size_t)p * 8) = f;
        return;
    }
    int t = threadIdx.x;
    if (t < 128) bnsum[t] = 0.0f;
    else bnsumsq[t - 128] = 0.0f;
}

// ---------------- A-fragment loaders ----------------
__device__ inline bf16x8 loadA(const float* ap) {
    float4 a0 = *(const float4*)ap;
    float4 a1 = *(const float4*)(ap + 4);
    bf16x8 f;
    f[0] = (bf16_t)a0.x; f[1] = (bf16_t)a0.y; f[2] = (bf16_t)a0.z; f[3] = (bf16_t)a0.w;
    f[4] = (bf16_t)a1.x; f[5] = (bf16_t)a1.y; f[6] = (bf16_t)a1.z; f[7] = (bf16_t)a1.w;
    return f;
}
__device__ inline bf16x8 loadA(const bf16_t* ap) { return *(const bf16x8*)ap; }

// ---------------- MFMA GEMM (K=128): norm / den+scale / bn-stats / zero-buf fusion ----------------
template <typename T, bool NORM>
__global__ __launch_bounds__(256) void gemm128s(const T* __restrict__ A,
                                                const bf16_t* __restrict__ Wp,
                                                const float* __restrict__ bias,
                                                const float* __restrict__ ksum_p,
                                                float* __restrict__ den_out,
                                                float* __restrict__ sums,
                                                float* __restrict__ sumsq,
                                                float* __restrict__ zero_buf, int zero_len,
                                                float* __restrict__ out,
                                                bf16_t* __restrict__ outb, int N) {
    __shared__ float lsum[128], lsq[128];
    int tid = threadIdx.x;
    if (zero_buf && blockIdx.x < 17) {  // zero kvs+ksum+vsum for the next kernel
        int base = (blockIdx.x * 256 + tid) * 4;
        if (base < zero_len) *(float4*)(zero_buf + base) = make_float4(0.f, 0.f, 0.f, 0.f);
    }
    int wave = tid >> 6;
    int lane = tid & 63;
    int quad = lane >> 4;
    int l16 = lane & 15;
    int m0 = blockIdx.x * 64 + wave * 16;
    int arow = m0 + l16;

    f32x4 acc[8] = {};
    #pragma unroll
    for (int kc = 0; kc < 4; kc++) {
        bf16x8 afrag = {};
        if (arow < N) afrag = loadA(A + ((size_t)arow << 7) + kc * 32 + quad * 8);
        bf16x8 bfr[8];
        #pragma unroll
        for (int t = 0; t < 8; t++)
            bfr[t] = *(const bf16x8*)(Wp + (size_t)(((t * 4 + kc) * 64) + lane) * 8);
        #pragma unroll
        for (int t = 0; t < 8; t++)
            acc[t] = __builtin_amdgcn_mfma_f32_16x16x32_bf16(afrag, bfr[t], acc[t], 0, 0, 0);
    }
    float vals[8][4];
    #pragma unroll
    for (int t = 0; t < 8; t++) {
        float b = bias ? bias[t * 16 + l16] : 0.0f;
        #pragma unroll
        for (int r = 0; r < 4; r++) vals[t][r] = acc[t][r] + b;
    }
    if (NORM) {
        #pragma unroll
        for (int r = 0; r < 4; r++) {
            float p = 0.0f;
            #pragma unroll
            for (int t = 0; t < 8; t++) p += vals[t][r] * vals[t][r];
            p += __shfl_xor(p, 1);
            p += __shfl_xor(p, 2);
            p += __shfl_xor(p, 4);
            p += __shfl_xor(p, 8);
            float inv = rsqrtf(p);
            #pragma unroll
            for (int t = 0; t < 8; t++) vals[t][r] *= inv;
        }
    }
    if (ksum_p) {  // fused den = qn . ksum + N; scale row by 1/den
        float kv[8];
        #pragma unroll
        for (int t = 0; t < 8; t++) kv[t] = ksum_p[t * 16 + l16];
        #pragma unroll
        for (int r = 0; r < 4; r++) {
            float dp = 0.0f;
            #pragma unroll
            for (int t = 0; t < 8; t++) dp += vals[t][r] * kv[t];
            dp += __shfl_xor(dp, 1);
            dp += __shfl_xor(dp, 2);
            dp += __shfl_xor(dp, 4);
            dp += __shfl_xor(dp, 8);
            float dv = dp + (float)NN;
            int rr = m0 + quad * 4 + r;
            if (l16 == 0 && rr < N) den_out[rr] = dv;
            float dinv = 1.0f / dv;
            #pragma unroll
            for (int t = 0; t < 8; t++) vals[t][r] *= dinv;
        }
    }
    #pragma unroll
    for (int r = 0; r < 4; r++) {
        int rr = m0 + quad * 4 + r;
        if (rr >= N) continue;
        #pragma unroll
        for (int t = 0; t < 8; t++) {
            int c = t * 16 + l16;
            float v = vals[t][r];
            if (out) out[((size_t)rr << 7) + c] = v;
            if (outb) outb[((size_t)rr << 7) + c] = (bf16_t)v;
        }
    }
    if (sums) {  // fused BN stats
        if (tid < 128) { lsum[tid] = 0.0f; lsq[tid] = 0.0f; }
        __syncthreads();
        float sp[8] = {}, qp[8] = {};
        #pragma unroll
        for (int r = 0; r < 4; r++) {
            int rr = m0 + quad * 4 + r;
            if (rr >= N) continue;
            #pragma unroll
            for (int t = 0; t < 8; t++) {
                float v = vals[t][r];
                sp[t] += v;
                qp[t] += v * v;
            }
        }
        #pragma unroll
        for (int t = 0; t < 8; t++) {
            sp[t] += __shfl_xor(sp[t], 16);
            sp[t] += __shfl_xor(sp[t], 32);
            qp[t] += __shfl_xor(qp[t], 16);
            qp[t] += __shfl_xor(qp[t], 32);
        }
        if (quad == 0) {
            #pragma unroll
            for (int t = 0; t < 8; t++) {
                atomicAdd(&lsum[t * 16 + l16], sp[t]);
                atomicAdd(&lsq[t * 16 + l16], qp[t]);
            }
        }
        __syncthreads();
        if (tid < 128) {
            atomicAdd(&sums[tid], lsum[tid]);
            atomicAdd(&sumsq[tid], lsq[tid]);
        }
    }
}

// ---------------- fc GEMM: single 640-K loop, 2 m-tiles/wave, fused BN stats ----------------
__global__ __launch_bounds__(256, 1) void gemm_fc(
    const bf16_t* __restrict__ qn, const bf16_t* __restrict__ s1, const bf16_t* __restrict__ s2,
    const bf16_t* __restrict__ s3, const bf16_t* __restrict__ s4,
    const bf16_t* __restrict__ WpM1, const bf16_t* __restrict__ Wp,
    const float* __restrict__ bvec, const float* __restrict__ bfc,
    const float* __restrict__ den, const bf16_t* __restrict__ resb,
    float* __restrict__ sums, float* __restrict__ sumsq,
    bf16_t* __restrict__ outb, int N) {
    __shared__ float lsum[128], lsq[128];
    const bf16_t* srcs[5] = {qn, s1, s2, s3, s4};
    int tid = threadIdx.x;
    int wave = tid >> 6;
    int lane = tid & 63;
    int quad = lane >> 4;
    int l16 = lane & 15;
    int m0 = blockIdx.x * 128 + wave * 32;  // 2 m-tiles per wave

    f32x4 acc[2][8] = {};
    #pragma unroll
    for (int kc = 0; kc < 20; kc++) {
        int s = kc >> 2;
        int klocal = (kc & 3) * 32;
        bf16x8 bfr[8];
        #pragma unroll
        for (int t = 0; t < 8; t++) {
            const bf16_t* bp = (kc < 4) ? WpM1 + (size_t)(((t * 4 + kc) * 64) + lane) * 8
                                        : Wp + (size_t)(((t * 20 + kc) * 64) + lane) * 8;
            bfr[t] = *(const bf16x8*)bp;
        }
        bf16x8 af[2] = {};
        #pragma unroll
        for (int m = 0; m < 2; m++) {
            int arow = m0 + m * 16 + l16;
            if (arow < N)
                af[m] = *(const bf16x8*)(srcs[s] + ((size_t)arow << 7) + klocal + quad * 8);
        }
        #pragma unroll
        for (int t = 0; t < 8; t++) {
            #pragma unroll
            for (int m = 0; m < 2; m++)
                acc[m][t] = __builtin_amdgcn_mfma_f32_16x16x32_bf16(af[m], bfr[t], acc[m][t],
                                                                    0, 0, 0);
        }
    }
    float bv[8], bf[8];
    #pragma unroll
    for (int t = 0; t < 8; t++) {
        bv[t] = bvec[t * 16 + l16];
        bf[t] = bfc[t * 16 + l16];
    }
    if (tid < 128) { lsum[tid] = 0.0f; lsq[tid] = 0.0f; }
    __syncthreads();
    float sp[8] = {}, qp[8] = {};
    #pragma unroll
    for (int m = 0; m < 2; m++) {
        #pragma unroll
        for (int r = 0; r < 4; r++) {
            int rr = m0 + m * 16 + quad * 4 + r;
            if (rr >= N) continue;
            float dinv = 1.0f / den[rr];
            #pragma unroll
            for (int t = 0; t < 8; t++) {
                int c = t * 16 + l16;
                float v = acc[m][t][r] + dinv * bv[t] + bf[t] +
                          (float)resb[((size_t)rr << 7) + c];
                outb[((size_t)rr << 7) + c] = (bf16_t)v;
                sp[t] += v;
                qp[t] += v * v;
            }
        }
    }
    #pragma unroll
    for (int t = 0; t < 8; t++) {
        sp[t] += __shfl_xor(sp[t], 16);
        sp[t] += __shfl_xor(sp[t], 32);
        qp[t] += __shfl_xor(qp[t], 16);
        qp[t] += __shfl_xor(qp[t], 32);
    }
    if (quad == 0) {
        #pragma unroll
        for (int t = 0; t < 8; t++) {
            atomicAdd(&lsum[t * 16 + l16], sp[t]);
            atomicAdd(&lsq[t * 16 + l16], qp[t]);
        }
    }
    __syncthreads();
    if (tid < 128) {
        atomicAdd(&sums[tid], lsum[tid]);
        atomicAdd(&sumsq[tid], lsq[tid]);
    }
}

// ---------------- out GEMM via MFMA ----------------
__global__ __launch_bounds__(256) void out_mfma(const bf16_t* __restrict__ hb,
                                                const bf16_t* __restrict__ Wp,
                                                const float* __restrict__ bias,
                                                float* __restrict__ out, int N) {
    int wave = threadIdx.x >> 6;
    int lane = threadIdx.x & 63;
    int quad = lane >> 4;
    int l16 = lane & 15;
    int m0 = blockIdx.x * 64 + wave * 16;
    int arow = m0 + l16;

    f32x4 acc[3] = {};
    #pragma unroll
    for (int kc = 0; kc < 4; kc++) {
        bf16x8 afrag = {};
        if (arow < N) afrag = *(const bf16x8*)(hb + ((size_t)arow << 7) + kc * 32 + quad * 8);
        #pragma unroll
        for (int t = 0; t < 3; t++) {
            const bf16_t* bp = Wp + (size_t)(((t * 4 + kc) * 64) + lane) * 8;
            acc[t] = __builtin_amdgcn_mfma_f32_16x16x32_bf16(afrag, *(const bf16x8*)bp, acc[t],
                                                             0, 0, 0);
        }
    }
    #pragma unroll
    for (int r = 0; r < 4; r++) {
        int rr = m0 + quad * 4 + r;
        if (rr >= N) continue;
        #pragma unroll
        for (int t = 0; t < 3; t++) {
            int c = t * 16 + l16;
            if (c < 40) out[(size_t)rr * 40 + c] = acc[t][r] + bias[c];
        }
    }
}

// ---------------- kvs via MFMA ----------------
__global__ __launch_bounds__(256) void kvs_mfma(const bf16_t* __restrict__ kn,
                                                const bf16_t* __restrict__ v,
                                                float* __restrict__ kvs,
                                                float* __restrict__ ksum,
                                                float* __restrict__ vsum, int N) {
    __shared__ bf16_t Lk[32][132];
    __shared__ bf16_t Lv[32][132];
    __shared__ float lred[256];
    int t = threadIdx.x;
    int wave = t >> 6, lane = t & 63, quad = lane >> 4, l16 = lane & 15;
    int tr = t >> 4, tc = (t & 15) * 8;
    int mbase = wave * 32;
    f32x4 acc[2][8] = {};
    float ks[8] = {}, vs[8] = {};
    for (int base = blockIdx.x * 32; base < N; base += gridDim.x * 32) {
        __syncthreads();
        #pragma unroll
        for (int hh = 0; hh < 2; hh++) {
            int r = hh * 16 + tr;
            int rowi = base + r;
            bf16x8 ck = {}, cv = {};
            if (rowi < N) {
                ck = *(const bf16x8*)(kn + ((size_t)rowi << 7) + tc);
                cv = *(const bf16x8*)(v + ((size_t)rowi << 7) + tc);
            }
            bf16x4 klo, khi, vlo, vhi;
            #pragma unroll
            for (int j = 0; j < 4; j++) {
                klo[j] = ck[j]; khi[j] = ck[j + 4];
                vlo[j] = cv[j]; vhi[j] = cv[j + 4];
                ks[j] += (float)ck[j]; ks[j + 4] += (float)ck[j + 4];
                vs[j] += (float)cv[j]; vs[j + 4] += (float)cv[j + 4];
            }
            *(bf16x4*)&Lk[r][tc] = klo;
            *(bf16x4*)&Lk[r][tc + 4] = khi;
            *(bf16x4*)&Lv[r][tc] = vlo;
            *(bf16x4*)&Lv[r][tc + 4] = vhi;
        }
        __syncthreads();
        bf16x8 af[2], bfr[8];
        #pragma unroll
        for (int mt = 0; mt < 2; mt++)
            #pragma unroll
            for (int j = 0; j < 8; j++) af[mt][j] = Lk[quad * 8 + j][mbase + mt * 16 + l16];
        #pragma unroll
        for (int tt = 0; tt < 8; tt++)
            #pragma unroll
            for (int j = 0; j < 8; j++) bfr[tt][j] = Lv[quad * 8 + j][tt * 16 + l16];
        #pragma unroll
        for (int mt = 0; mt < 2; mt++)
            #pragma unroll
            for (int tt = 0; tt < 8; tt++)
                acc[mt][tt] = __builtin_amdgcn_mfma_f32_16x16x32_bf16(af[mt], bfr[tt],
                                                                      acc[mt][tt], 0, 0, 0);
    }
    #pragma unroll
    for (int mt = 0; mt < 2; mt++)
        #pragma unroll
        for (int tt = 0; tt < 8; tt++)
            #pragma unroll
            for (int r = 0; r < 4; r++) {
                int m = mbase + mt * 16 + quad * 4 + r;
                int d = tt * 16 + l16;
                atomicAdd(&kvs[m * HD + d], acc[mt][tt][r]);
            }
    lred[t] = 0.0f;
    __syncthreads();
    #pragma unroll
    for (int j = 0; j < 8; j++) {
        atomicAdd(&lred[tc + j], ks[j]);
        atomicAdd(&lred[128 + tc + j], vs[j]);
    }
    __syncthreads();
    if (t < 128) {
        atomicAdd(&ksum[t], lred[t]);
        atomicAdd(&vsum[t], lred[t + 128]);
    }
}

// ---------------- M1 = kvs @ W0 (frag-packed), bvec = vsum @ W0, zero BN stats ----------------
__global__ void m1_pack(const float* __restrict__ kvs, const float* __restrict__ W0,
                        const float* __restrict__ vsum, bf16_t* __restrict__ WpM1,
                        float* __restrict__ bvec, float* __restrict__ bnsum,
                        float* __restrict__ bnsumsq) {
    if (blockIdx.x == 64) {
        int t = threadIdx.x;
        if (t < 128) {
            bnsum[t] = 0.0f;
            float acc = 0.0f;
            for (int d = 0; d < 128; d++) acc += vsum[d] * W0[d * 128 + t];
            bvec[t] = acc;
        } else {
            bnsumsq[t - 128] = 0.0f;
        }
        return;
    }
    int idx = blockIdx.x * 256 + threadIdx.x;
    int m = idx >> 7;
    int c = idx & 127;
    float acc = 0.0f;
    for (int d = 0; d < 128; d += 4) {
        float4 k4 = *(const float4*)(kvs + m * 128 + d);
        acc += k4.x * W0[(d + 0) * 128 + c] + k4.y * W0[(d + 1) * 128 + c] +
               k4.z * W0[(d + 2) * 128 + c] + k4.w * W0[(d + 3) * 128 + c];
    }
    int t = c >> 4, l16 = c & 15, kc = m >> 5, quad = (m >> 3) & 3, j = m & 7;
    int lane = quad * 16 + l16;
    WpM1[(size_t)(((t * 4 + kc) * 64) + lane) * 8 + j] = (bf16_t)acc;
}

// ---------------- BN apply (finalize fused per block) ----------------
__global__ void bn_apply2(const bf16_t* __restrict__ z, bf16_t* __restrict__ hb,
                          const float* __restrict__ sums, const float* __restrict__ sumsq,
                          const float* __restrict__ g, const float* __restrict__ bb, int n4) {
    __shared__ float sc[128], sh[128];
    int t = threadIdx.x;
    if (t < 128) {
        float m = sums[t] / (float)NN;
        float var = sumsq[t] / (float)NN - m * m;
        float s = g[t] * rsqrtf(var + EPS_BN);
        sc[t] = s;
        sh[t] = bb[t] - m * s;
    }
    __syncthreads();
    int i = blockIdx.x * 256 + t;
    if (i >= n4) return;
    int c4 = (i & 31) * 4;
    bf16x4 zv = *(const bf16x4*)(z + (size_t)i * 4);
    bf16x4 o;
    #pragma unroll
    for (int j = 0; j < 4; j++)
        o[j] = (bf16_t)fmaxf((float)zv[j] * sc[c4 + j] + sh[c4 + j], 0.0f);
    *(bf16x4*)(hb + (size_t)i * 4) = o;
}

extern "C" void kernel_launch(void* const* d_in, const int* in_sizes, int n_in,
                              void* d_out, int out_size, void* d_ws, size_t ws_size,
                              hipStream_t stream) {
    const float* x = (const float*)d_in[0];
    const int* eidx = (const int*)d_in[1];
    const float* W_in = (const float*)d_in[2];
    const float* b_in = (const float*)d_in[3];
    const float* Wq = (const float*)d_in[4];
    const float* bq = (const float*)d_in[5];
    const float* Wk = (const float*)d_in[6];
    const float* bk = (const float*)d_in[7];
    const float* Wfc = (const float*)d_in[8];
    const float* bfc = (const float*)d_in[9];
    const float* W_out = (const float*)d_in[10];
    const float* b_out = (const float*)d_in[11];
    const float* bn_g = (const float*)d_in[12];
    const float* bn_b = (const float*)d_in[13];
    float* out = (float*)d_out;

    const int N = NN, E = NE;
    const int* rowp = eidx;
    const int* colp = eidx + E;

    char* ws = (char*)d_ws;
    size_t off = 0;
    auto nxt = [&](size_t bytes) -> void* {
        void* p = ws + off;
        off += (bytes + 255) & ~(size_t)255;
        return p;
    };
    int* counts = (int*)nxt((size_t)N * 4);
    int* cursor = (int*)nxt((size_t)N * 4);  // adjacent to counts: one memset covers both
    int* offsets = (int*)nxt((size_t)(N + 1) * 4);
    int* bsum = (int*)nxt(1024);
    int2* edges = (int2*)nxt((size_t)E * 8);
    float* dis = (float*)nxt((size_t)N * 4);
    float* den = (float*)nxt((size_t)N * 4);
    float* kvs = (float*)nxt((size_t)HD * HD * 4);  // + ksum + vsum contiguous
    float* ksum = (float*)nxt((size_t)HD * 4);
    float* vsum = (float*)nxt((size_t)HD * 4);
    float* bnsum = (float*)nxt((size_t)HD * 4);
    float* bnsumsq = (float*)nxt((size_t)HD * 4);
    float* bvec = (float*)nxt((size_t)HD * 4);
    // bf16 activations
    bf16_t* zb = (bf16_t*)nxt((size_t)N * HD * 2);
    bf16_t* hb = (bf16_t*)nxt((size_t)N * HD * 2);
    bf16_t* p1b = (bf16_t*)nxt((size_t)N * HD * 2);
    bf16_t* p2b = (bf16_t*)nxt((size_t)N * HD * 2);
    bf16_t* p3b = (bf16_t*)nxt((size_t)N * HD * 2);
    bf16_t* knb = (bf16_t*)nxt((size_t)N * HD * 2);
    bf16_t* qnb = (bf16_t*)nxt((size_t)N * HD * 2);
    // fragment-packed bf16 weights
    bf16_t* Wp_in = (bf16_t*)nxt((size_t)8 * 4 * 64 * 8 * 2);
    bf16_t* Wp_q = (bf16_t*)nxt((size_t)2 * 8 * 4 * 64 * 8 * 2);
    bf16_t* Wp_k = (bf16_t*)nxt((size_t)2 * 8 * 4 * 64 * 8 * 2);
    bf16_t* Wp_fc = (bf16_t*)nxt((size_t)2 * 8 * 20 * 64 * 8 * 2);
    bf16_t* WpM1 = (bf16_t*)nxt((size_t)8 * 4 * 64 * 8 * 2);
    bf16_t* Wp_out = (bf16_t*)nxt((size_t)3 * 4 * 64 * 8 * 2);

    const int GB = (N + 63) / 64;
    const int GB2 = (N + 127) / 128;
    const int QSZ = HD * HD;
    const int FSZ = 8 * 20 * 64 * 8;
    const int NB = (N + 255) / 256;

    // ---- CSR build ----
    hipMemsetAsync(counts, 0, (size_t)2 * ((N * 4 + 255) & ~255), stream);
    count_edges<<<(E + 255) / 256, 256, 0, stream>>>(colp, counts, E);
    scan1<<<NB, 256, 0, stream>>>(counts, offsets, bsum, dis, N);
    scan2<<<1, 256, 0, stream>>>(bsum, offsets, NB, N);
    scan3<<<NB, 256, 0, stream>>>(offsets, bsum, N);
    scatter_edges2<<<(E + 255) / 256, 256, 0, stream>>>(rowp, colp, dis, offsets, cursor,
                                                        edges, E);

    // ---- all weight packing + zero BN stats (one launch) ----
    wcvt_all<<<124, 256, 0, stream>>>(W_in, Wq, Wk, Wfc, W_out, Wp_in, Wp_q, Wp_k, Wp_fc,
                                      Wp_out, bnsum, bnsumsq);

    // ---- input layer (fused BN stats) ----
    gemm128s<float, false><<<GB, 256, 0, stream>>>(x, Wp_in, b_in, nullptr, nullptr, bnsum,
                                                   bnsumsq, nullptr, 0, nullptr, zb, N);
    bn_apply2<<<(N * 32 + 255) / 256, 256, 0, stream>>>(zb, hb, bnsum, bnsumsq, bn_g, bn_b,
                                                        N * 32);

    for (int i = 0; i < 2; i++) {
        const float* bq_i = bq + (size_t)i * HD;
        const float* bk_i = bk + (size_t)i * HD;
        const float* bfc_i = bfc + (size_t)i * HD;
        const float* Wfc_i = Wfc + (size_t)i * 640 * HD;  // rows 0..127 = W0
        bf16_t* Wp_q_i = Wp_q + (size_t)i * QSZ;
        bf16_t* Wp_k_i = Wp_k + (size_t)i * QSZ;
        bf16_t* Wp_fc_i = Wp_fc + (size_t)i * FSZ;

        // K-hop diffusion (bf16)
        prop_b2<<<(N + 3) / 4, 256, 0, stream>>>(offsets, edges, hb, p1b);
        prop_b2<<<(N + 3) / 4, 256, 0, stream>>>(offsets, edges, p1b, p2b);
        prop_b2<<<(N + 3) / 4, 256, 0, stream>>>(offsets, edges, p2b, p3b);

        // attention: k-gemm (also zeroes kvs+ksum+vsum), kvs, q-gemm (fused den)
        gemm128s<bf16_t, true><<<GB, 256, 0, stream>>>(hb, Wp_k_i, bk_i, nullptr, nullptr,
                                                       nullptr, nullptr, kvs, HD * HD + 2 * HD,
                                                       nullptr, knb, N);
        kvs_mfma<<<256, 256, 0, stream>>>(knb, hb, kvs, ksum, vsum, N);
        gemm128s<bf16_t, true><<<GB, 256, 0, stream>>>(hb, Wp_q_i, bq_i, ksum, den, nullptr,
                                                       nullptr, nullptr, 0, nullptr, qnb, N);
        m1_pack<<<65, 256, 0, stream>>>(kvs, Wfc_i, vsum, WpM1, bvec, bnsum, bnsumsq);

        // z = qn@M1 + dinv*bvec + [h,p1,p2,p3]@W[128:] + bfc + hb  (fused BN stats)
        gemm_fc<<<GB2, 256, 0, stream>>>(qnb, hb, p1b, p2b, p3b, WpM1, Wp_fc_i, bvec, bfc_i,
                                         den, hb, bnsum, bnsumsq, zb, N);
        bn_apply2<<<(N * 32 + 255) / 256, 256, 0, stream>>>(zb, hb, bnsum, bnsumsq,
                                                            bn_g + (size_t)(i + 1) * HD,
                                                            bn_b + (size_t)(i + 1) * HD,
                                                            N * 32);
    }

    out_mfma<<<GB, 256, 0, stream>>>(hb, Wp_out, b_out, out, N);
}

// Round 11
// 615.464 us; speedup vs baseline: 1.1350x; 1.0456x over previous
//
#include <hip/hip_runtime.h>
#include <hip/hip_bf16.h>
#include <math.h>

#define NN 50000
#define NE 800000
#define HD 128
#define EPS_BN 1e-5f

typedef __bf16 bf16_t;
typedef bf16_t bf16x8 __attribute__((ext_vector_type(8)));
typedef bf16_t bf16x4 __attribute__((ext_vector_type(4)));
typedef float f32x4 __attribute__((ext_vector_type(4)));

// ---------------- CSR build ----------------
__global__ void count_edges(const int* __restrict__ col, int* __restrict__ counts, int E) {
    int e = blockIdx.x * 256 + threadIdx.x;
    if (e >= E) return;
    atomicAdd(&counts[col[e]], 1);
}

// scan1 + dis fused
__global__ __launch_bounds__(256) void scan1(const int* __restrict__ counts,
                                             int* __restrict__ offsets,
                                             int* __restrict__ bsum,
                                             float* __restrict__ dis, int n) {
    __shared__ int wsl[4];
    int t = threadIdx.x, lane = t & 63, w = t >> 6;
    int i = blockIdx.x * 256 + t;
    int v = (i < n) ? counts[i] : 0;
    if (i < n) dis[i] = (v > 0) ? rsqrtf((float)v) : 0.0f;
    int x = v;
    #pragma unroll
    for (int o = 1; o < 64; o <<= 1) {
        int tt = __shfl_up(x, o, 64);
        if (lane >= o) x += tt;
    }
    if (lane == 63) wsl[w] = x;
    __syncthreads();
    if (t == 0) {
        int s = 0;
        #pragma unroll
        for (int k = 0; k < 4; k++) { int tmp = wsl[k]; wsl[k] = s; s += tmp; }
        bsum[blockIdx.x] = s;
    }
    __syncthreads();
    if (i < n) offsets[i] = x - v + wsl[w];
}

__global__ __launch_bounds__(256) void scan2(int* __restrict__ bsum, int* __restrict__ offsets,
                                             int nb, int n) {
    __shared__ int wsl[4];
    int t = threadIdx.x, lane = t & 63, w = t >> 6;
    int v = (t < nb) ? bsum[t] : 0;
    int x = v;
    #pragma unroll
    for (int o = 1; o < 64; o <<= 1) {
        int tt = __shfl_up(x, o, 64);
        if (lane >= o) x += tt;
    }
    if (lane == 63) wsl[w] = x;
    __syncthreads();
    if (t == 0) {
        int s = 0;
        #pragma unroll
        for (int k = 0; k < 4; k++) { int tmp = wsl[k]; wsl[k] = s; s += tmp; }
    }
    __syncthreads();
    int excl = x - v + wsl[w];
    if (t < nb) bsum[t] = excl;
    if (t == nb - 1) offsets[n] = excl + v;
}

__global__ void scan3(int* __restrict__ offsets, const int* __restrict__ bsum, int n) {
    int i = blockIdx.x * 256 + threadIdx.x;
    if (i < n) offsets[i] += bsum[blockIdx.x];
}

__global__ void scatter_edges2(const int* __restrict__ row, const int* __restrict__ col,
                               const float* __restrict__ dis, const int* __restrict__ offsets,
                               int* __restrict__ cursor, int2* __restrict__ edges, int E) {
    int e = blockIdx.x * 256 + threadIdx.x;
    if (e >= E) return;
    int c = col[e], r = row[e];
    int pos = offsets[c] + atomicAdd(&cursor[c], 1);
    edges[pos] = make_int2(r, __float_as_int(dis[c] * dis[r]));
}

// ---------------- Graph propagation: 1 wave/node, 4 quarters x 16B lanes, 2-edge unroll ----------------
__global__ __launch_bounds__(256) void prop_b3(const int* __restrict__ offsets,
                                               const int2* __restrict__ edges,
                                               const bf16_t* __restrict__ in,
                                               bf16_t* __restrict__ out) {
    int wave = threadIdx.x >> 6;
    int lane = threadIdx.x & 63;
    int q = lane >> 4;         // quarter 0..3
    int ch8 = (lane & 15) * 8;  // 8 channels per lane
    int c = blockIdx.x * 4 + wave;
    if (c >= NN) return;
    int s = offsets[c], e = offsets[c + 1];
    float a[8] = {};
    int i = s + q;
    for (; i + 4 < e; i += 8) {  // 2 edges per quarter per iter (8 gathers in flight per wave)
        int2 r0 = edges[i], r1 = edges[i + 4];
        bf16x8 v0 = *(const bf16x8*)(in + ((size_t)r0.x << 7) + ch8);
        bf16x8 v1 = *(const bf16x8*)(in + ((size_t)r1.x << 7) + ch8);
        float w0 = __int_as_float(r0.y), w1 = __int_as_float(r1.y);
        #pragma unroll
        for (int j = 0; j < 8; j++) a[j] += w0 * (float)v0[j] + w1 * (float)v1[j];
    }
    for (; i < e; i += 4) {
        int2 r0 = edges[i];
        bf16x8 v0 = *(const bf16x8*)(in + ((size_t)r0.x << 7) + ch8);
        float w0 = __int_as_float(r0.y);
        #pragma unroll
        for (int j = 0; j < 8; j++) a[j] += w0 * (float)v0[j];
    }
    #pragma unroll
    for (int j = 0; j < 8; j++) {
        a[j] += __shfl_xor(a[j], 16);
        a[j] += __shfl_xor(a[j], 32);
    }
    if (q == 0) {
        bf16x8 o;
        #pragma unroll
        for (int j = 0; j < 8; j++) o[j] = (bf16_t)a[j];
        *(bf16x8*)(out + ((size_t)c << 7) + ch8) = o;
    }
}

// ---------------- Mega weight-pack kernel ----------------
__device__ inline void pack_frag(const float* __restrict__ W, bf16_t* __restrict__ Wp, int nkc,
                                 int lb) {
    int p = lb * 256 + threadIdx.x;
    if (p >= 8 * nkc * 64) return;
    int lane = p & 63;
    int tk = p >> 6;
    int kc = tk % nkc;
    int t = tk / nkc;
    int n = t * 16 + (lane & 15);
    int k0 = kc * 32 + (lane >> 4) * 8;
    bf16x8 f;
    #pragma unroll
    for (int j = 0; j < 8; j++) f[j] = (bf16_t)W[(size_t)(k0 + j) * 128 + n];
    *(bf16x8*)(Wp + (size_t)p * 8) = f;
}

__global__ void wcvt_all(const float* __restrict__ W_in, const float* __restrict__ Wq,
                         const float* __restrict__ Wk, const float* __restrict__ Wfc,
                         const float* __restrict__ W_out, bf16_t* __restrict__ Wp_in,
                         bf16_t* __restrict__ Wp_q, bf16_t* __restrict__ Wp_k,
                         bf16_t* __restrict__ Wp_fc, bf16_t* __restrict__ Wp_out,
                         float* __restrict__ bnsum, float* __restrict__ bnsumsq) {
    const int QSZ = HD * HD;
    const int FSZ = 8 * 20 * 64 * 8;
    int b = blockIdx.x;
    if (b < 8) { pack_frag(W_in, Wp_in, 4, b); return; }
    if (b < 16) { pack_frag(Wq, Wp_q, 4, b - 8); return; }
    if (b < 24) { pack_frag(Wq + QSZ, Wp_q + QSZ, 4, b - 16); return; }
    if (b < 32) { pack_frag(Wk, Wp_k, 4, b - 24); return; }
    if (b < 40) { pack_frag(Wk + QSZ, Wp_k + QSZ, 4, b - 32); return; }
    if (b < 80) { pack_frag(Wfc, Wp_fc, 20, b - 40); return; }
    if (b < 120) { pack_frag(Wfc + 640 * HD, Wp_fc + FSZ, 20, b - 80); return; }
    if (b < 123) {  // W_out [128][40] -> 3 tiles padded to 48
        int p = (b - 120) * 256 + threadIdx.x;
        if (p >= 3 * 4 * 64) return;
        int lane = p & 63;
        int tk = p >> 6;
        int kc = tk & 3;
        int t = tk >> 2;
        int n = t * 16 + (lane & 15);
        int k0 = kc * 32 + (lane >> 4) * 8;
        bf16x8 f;
        #pragma unroll
        for (int j = 0; j < 8; j++)
            f[j] = (n < 40) ? (bf16_t)W_out[(size_t)(k0 + j) * 40 + n] : (bf16_t)0.0f;
        *(bf16x8*)(Wp_out + (size_t)p * 8) = f;
        return;
    }
    int t = threadIdx.x;
    if (t < 128) bnsum[t] = 0.0f;
    else bnsumsq[t - 128] = 0.0f;
}

// ---------------- A-fragment loaders ----------------
__device__ inline bf16x8 loadA(const float* ap) {
    float4 a0 = *(const float4*)ap;
    float4 a1 = *(const float4*)(ap + 4);
    bf16x8 f;
    f[0] = (bf16_t)a0.x; f[1] = (bf16_t)a0.y; f[2] = (bf16_t)a0.z; f[3] = (bf16_t)a0.w;
    f[4] = (bf16_t)a1.x; f[5] = (bf16_t)a1.y; f[6] = (bf16_t)a1.z; f[7] = (bf16_t)a1.w;
    return f;
}
__device__ inline bf16x8 loadA(const bf16_t* ap) { return *(const bf16x8*)ap; }

// ---------------- MFMA GEMM (K=128): batched A-loads; norm / den+scale / bn-stats / zero-buf ----------------
template <typename T, bool NORM>
__global__ __launch_bounds__(256) void gemm128s(const T* __restrict__ A,
                                                const bf16_t* __restrict__ Wp,
                                                const float* __restrict__ bias,
                                                const float* __restrict__ ksum_p,
                                                float* __restrict__ den_out,
                                                float* __restrict__ sums,
                                                float* __restrict__ sumsq,
                                                float* __restrict__ zero_buf, int zero_len,
                                                float* __restrict__ out,
                                                bf16_t* __restrict__ outb, int N) {
    __shared__ float lsum[128], lsq[128];
    int tid = threadIdx.x;
    if (zero_buf && blockIdx.x < 17) {  // zero kvs+ksum+vsum for the next kernel
        int base = (blockIdx.x * 256 + tid) * 4;
        if (base < zero_len) *(float4*)(zero_buf + base) = make_float4(0.f, 0.f, 0.f, 0.f);
    }
    int wave = tid >> 6;
    int lane = tid & 63;
    int quad = lane >> 4;
    int l16 = lane & 15;
    int m0 = blockIdx.x * 64 + wave * 16;
    int arow = m0 + l16;

    // batch all A-fragment loads (8 cold loads in flight for fp32 A)
    bf16x8 afr[4];
    if (arow < N) {
        #pragma unroll
        for (int kc = 0; kc < 4; kc++)
            afr[kc] = loadA(A + ((size_t)arow << 7) + kc * 32 + quad * 8);
    } else {
        #pragma unroll
        for (int kc = 0; kc < 4; kc++) afr[kc] = (bf16x8){};
    }

    f32x4 acc[8] = {};
    #pragma unroll
    for (int kc = 0; kc < 4; kc++) {
        bf16x8 bfr[8];
        #pragma unroll
        for (int t = 0; t < 8; t++)
            bfr[t] = *(const bf16x8*)(Wp + (size_t)(((t * 4 + kc) * 64) + lane) * 8);
        #pragma unroll
        for (int t = 0; t < 8; t++)
            acc[t] = __builtin_amdgcn_mfma_f32_16x16x32_bf16(afr[kc], bfr[t], acc[t], 0, 0, 0);
    }
    float vals[8][4];
    #pragma unroll
    for (int t = 0; t < 8; t++) {
        float b = bias ? bias[t * 16 + l16] : 0.0f;
        #pragma unroll
        for (int r = 0; r < 4; r++) vals[t][r] = acc[t][r] + b;
    }
    if (NORM) {
        #pragma unroll
        for (int r = 0; r < 4; r++) {
            float p = 0.0f;
            #pragma unroll
            for (int t = 0; t < 8; t++) p += vals[t][r] * vals[t][r];
            p += __shfl_xor(p, 1);
            p += __shfl_xor(p, 2);
            p += __shfl_xor(p, 4);
            p += __shfl_xor(p, 8);
            float inv = rsqrtf(p);
            #pragma unroll
            for (int t = 0; t < 8; t++) vals[t][r] *= inv;
        }
    }
    if (ksum_p) {  // fused den = qn . ksum + N; scale row by 1/den
        float kv[8];
        #pragma unroll
        for (int t = 0; t < 8; t++) kv[t] = ksum_p[t * 16 + l16];
        #pragma unroll
        for (int r = 0; r < 4; r++) {
            float dp = 0.0f;
            #pragma unroll
            for (int t = 0; t < 8; t++) dp += vals[t][r] * kv[t];
            dp += __shfl_xor(dp, 1);
            dp += __shfl_xor(dp, 2);
            dp += __shfl_xor(dp, 4);
            dp += __shfl_xor(dp, 8);
            float dv = dp + (float)NN;
            int rr = m0 + quad * 4 + r;
            if (l16 == 0 && rr < N) den_out[rr] = dv;
            float dinv = 1.0f / dv;
            #pragma unroll
            for (int t = 0; t < 8; t++) vals[t][r] *= dinv;
        }
    }
    #pragma unroll
    for (int r = 0; r < 4; r++) {
        int rr = m0 + quad * 4 + r;
        if (rr >= N) continue;
        #pragma unroll
        for (int t = 0; t < 8; t++) {
            int c = t * 16 + l16;
            float v = vals[t][r];
            if (out) out[((size_t)rr << 7) + c] = v;
            if (outb) outb[((size_t)rr << 7) + c] = (bf16_t)v;
        }
    }
    if (sums) {  // fused BN stats
        if (tid < 128) { lsum[tid] = 0.0f; lsq[tid] = 0.0f; }
        __syncthreads();
        float sp[8] = {}, qp[8] = {};
        #pragma unroll
        for (int r = 0; r < 4; r++) {
            int rr = m0 + quad * 4 + r;
            if (rr >= N) continue;
            #pragma unroll
            for (int t = 0; t < 8; t++) {
                float v = vals[t][r];
                sp[t] += v;
                qp[t] += v * v;
            }
        }
        #pragma unroll
        for (int t = 0; t < 8; t++) {
            sp[t] += __shfl_xor(sp[t], 16);
            sp[t] += __shfl_xor(sp[t], 32);
            qp[t] += __shfl_xor(qp[t], 16);
            qp[t] += __shfl_xor(qp[t], 32);
        }
        if (quad == 0) {
            #pragma unroll
            for (int t = 0; t < 8; t++) {
                atomicAdd(&lsum[t * 16 + l16], sp[t]);
                atomicAdd(&lsq[t * 16 + l16], qp[t]);
            }
        }
        __syncthreads();
        if (tid < 128) {
            atomicAdd(&sums[tid], lsum[tid]);
            atomicAdd(&sumsq[tid], lsq[tid]);
        }
    }
}

// ---------------- fc GEMM: single 640-K loop, 2 m-tiles/wave, fused BN stats ----------------
__global__ __launch_bounds__(256, 1) void gemm_fc(
    const bf16_t* __restrict__ qn, const bf16_t* __restrict__ s1, const bf16_t* __restrict__ s2,
    const bf16_t* __restrict__ s3, const bf16_t* __restrict__ s4,
    const bf16_t* __restrict__ WpM1, const bf16_t* __restrict__ Wp,
    const float* __restrict__ bvec, const float* __restrict__ bfc,
    const float* __restrict__ den, const bf16_t* __restrict__ resb,
    float* __restrict__ sums, float* __restrict__ sumsq,
    bf16_t* __restrict__ outb, int N) {
    __shared__ float lsum[128], lsq[128];
    const bf16_t* srcs[5] = {qn, s1, s2, s3, s4};
    int tid = threadIdx.x;
    int wave = tid >> 6;
    int lane = tid & 63;
    int quad = lane >> 4;
    int l16 = lane & 15;
    int m0 = blockIdx.x * 128 + wave * 32;  // 2 m-tiles per wave

    f32x4 acc[2][8] = {};
    #pragma unroll
    for (int kc = 0; kc < 20; kc++) {
        int s = kc >> 2;
        int klocal = (kc & 3) * 32;
        bf16x8 bfr[8];
        #pragma unroll
        for (int t = 0; t < 8; t++) {
            const bf16_t* bp = (kc < 4) ? WpM1 + (size_t)(((t * 4 + kc) * 64) + lane) * 8
                                        : Wp + (size_t)(((t * 20 + kc) * 64) + lane) * 8;
            bfr[t] = *(const bf16x8*)bp;
        }
        bf16x8 af[2] = {};
        #pragma unroll
        for (int m = 0; m < 2; m++) {
            int arow = m0 + m * 16 + l16;
            if (arow < N)
                af[m] = *(const bf16x8*)(srcs[s] + ((size_t)arow << 7) + klocal + quad * 8);
        }
        #pragma unroll
        for (int t = 0; t < 8; t++) {
            #pragma unroll
            for (int m = 0; m < 2; m++)
                acc[m][t] = __builtin_amdgcn_mfma_f32_16x16x32_bf16(af[m], bfr[t], acc[m][t],
                                                                    0, 0, 0);
        }
    }
    float bv[8], bf[8];
    #pragma unroll
    for (int t = 0; t < 8; t++) {
        bv[t] = bvec[t * 16 + l16];
        bf[t] = bfc[t * 16 + l16];
    }
    if (tid < 128) { lsum[tid] = 0.0f; lsq[tid] = 0.0f; }
    __syncthreads();
    float sp[8] = {}, qp[8] = {};
    #pragma unroll
    for (int m = 0; m < 2; m++) {
        #pragma unroll
        for (int r = 0; r < 4; r++) {
            int rr = m0 + m * 16 + quad * 4 + r;
            if (rr >= N) continue;
            float dinv = 1.0f / den[rr];
            #pragma unroll
            for (int t = 0; t < 8; t++) {
                int c = t * 16 + l16;
                float v = acc[m][t][r] + dinv * bv[t] + bf[t] +
                          (float)resb[((size_t)rr << 7) + c];
                outb[((size_t)rr << 7) + c] = (bf16_t)v;
                sp[t] += v;
                qp[t] += v * v;
            }
        }
    }
    #pragma unroll
    for (int t = 0; t < 8; t++) {
        sp[t] += __shfl_xor(sp[t], 16);
        sp[t] += __shfl_xor(sp[t], 32);
        qp[t] += __shfl_xor(qp[t], 16);
        qp[t] += __shfl_xor(qp[t], 32);
    }
    if (quad == 0) {
        #pragma unroll
        for (int t = 0; t < 8; t++) {
            atomicAdd(&lsum[t * 16 + l16], sp[t]);
            atomicAdd(&lsq[t * 16 + l16], qp[t]);
        }
    }
    __syncthreads();
    if (tid < 128) {
        atomicAdd(&sums[tid], lsum[tid]);
        atomicAdd(&sumsq[tid], lsq[tid]);
    }
}

// ---------------- out GEMM via MFMA ----------------
__global__ __launch_bounds__(256) void out_mfma(const bf16_t* __restrict__ hb,
                                                const bf16_t* __restrict__ Wp,
                                                const float* __restrict__ bias,
                                                float* __restrict__ out, int N) {
    int wave = threadIdx.x >> 6;
    int lane = threadIdx.x & 63;
    int quad = lane >> 4;
    int l16 = lane & 15;
    int m0 = blockIdx.x * 64 + wave * 16;
    int arow = m0 + l16;

    bf16x8 afr[4];
    if (arow < N) {
        #pragma unroll
        for (int kc = 0; kc < 4; kc++)
            afr[kc] = *(const bf16x8*)(hb + ((size_t)arow << 7) + kc * 32 + quad * 8);
    } else {
        #pragma unroll
        for (int kc = 0; kc < 4; kc++) afr[kc] = (bf16x8){};
    }
    f32x4 acc[3] = {};
    #pragma unroll
    for (int kc = 0; kc < 4; kc++) {
        #pragma unroll
        for (int t = 0; t < 3; t++) {
            const bf16_t* bp = Wp + (size_t)(((t * 4 + kc) * 64) + lane) * 8;
            acc[t] = __builtin_amdgcn_mfma_f32_16x16x32_bf16(afr[kc], *(const bf16x8*)bp,
                                                             acc[t], 0, 0, 0);
        }
    }
    #pragma unroll
    for (int r = 0; r < 4; r++) {
        int rr = m0 + quad * 4 + r;
        if (rr >= N) continue;
        #pragma unroll
        for (int t = 0; t < 3; t++) {
            int c = t * 16 + l16;
            if (c < 40) out[(size_t)rr * 40 + c] = acc[t][r] + bias[c];
        }
    }
}

// ---------------- kvs via MFMA ----------------
__global__ __launch_bounds__(256) void kvs_mfma(const bf16_t* __restrict__ kn,
                                                const bf16_t* __restrict__ v,
                                                float* __restrict__ kvs,
                                                float* __restrict__ ksum,
                                                float* __restrict__ vsum, int N) {
    __shared__ bf16_t Lk[32][132];
    __shared__ bf16_t Lv[32][132];
    __shared__ float lred[256];
    int t = threadIdx.x;
    int wave = t >> 6, lane = t & 63, quad = lane >> 4, l16 = lane & 15;
    int tr = t >> 4, tc = (t & 15) * 8;
    int mbase = wave * 32;
    f32x4 acc[2][8] = {};
    float ks[8] = {}, vs[8] = {};
    for (int base = blockIdx.x * 32; base < N; base += gridDim.x * 32) {
        __syncthreads();
        #pragma unroll
        for (int hh = 0; hh < 2; hh++) {
            int r = hh * 16 + tr;
            int rowi = base + r;
            bf16x8 ck = {}, cv = {};
            if (rowi < N) {
                ck = *(const bf16x8*)(kn + ((size_t)rowi << 7) + tc);
                cv = *(const bf16x8*)(v + ((size_t)rowi << 7) + tc);
            }
            bf16x4 klo, khi, vlo, vhi;
            #pragma unroll
            for (int j = 0; j < 4; j++) {
                klo[j] = ck[j]; khi[j] = ck[j + 4];
                vlo[j] = cv[j]; vhi[j] = cv[j + 4];
                ks[j] += (float)ck[j]; ks[j + 4] += (float)ck[j + 4];
                vs[j] += (float)cv[j]; vs[j + 4] += (float)cv[j + 4];
            }
            *(bf16x4*)&Lk[r][tc] = klo;
            *(bf16x4*)&Lk[r][tc + 4] = khi;
            *(bf16x4*)&Lv[r][tc] = vlo;
            *(bf16x4*)&Lv[r][tc + 4] = vhi;
        }
        __syncthreads();
        bf16x8 af[2], bfr[8];
        #pragma unroll
        for (int mt = 0; mt < 2; mt++)
            #pragma unroll
            for (int j = 0; j < 8; j++) af[mt][j] = Lk[quad * 8 + j][mbase + mt * 16 + l16];
        #pragma unroll
        for (int tt = 0; tt < 8; tt++)
            #pragma unroll
            for (int j = 0; j < 8; j++) bfr[tt][j] = Lv[quad * 8 + j][tt * 16 + l16];
        #pragma unroll
        for (int mt = 0; mt < 2; mt++)
            #pragma unroll
            for (int tt = 0; tt < 8; tt++)
                acc[mt][tt] = __builtin_amdgcn_mfma_f32_16x16x32_bf16(af[mt], bfr[tt],
                                                                      acc[mt][tt], 0, 0, 0);
    }
    #pragma unroll
    for (int mt = 0; mt < 2; mt++)
        #pragma unroll
        for (int tt = 0; tt < 8; tt++)
            #pragma unroll
            for (int r = 0; r < 4; r++) {
                int m = mbase + mt * 16 + quad * 4 + r;
                int d = tt * 16 + l16;
                atomicAdd(&kvs[m * HD + d], acc[mt][tt][r]);
            }
    lred[t] = 0.0f;
    __syncthreads();
    #pragma unroll
    for (int j = 0; j < 8; j++) {
        atomicAdd(&lred[tc + j], ks[j]);
        atomicAdd(&lred[128 + tc + j], vs[j]);
    }
    __syncthreads();
    if (t < 128) {
        atomicAdd(&ksum[t], lred[t]);
        atomicAdd(&vsum[t], lred[t + 128]);
    }
}

// ---------------- M1 = kvs @ W0 (frag-packed), bvec = vsum @ W0, zero BN stats ----------------
__global__ void m1_pack(const float* __restrict__ kvs, const float* __restrict__ W0,
                        const float* __restrict__ vsum, bf16_t* __restrict__ WpM1,
                        float* __restrict__ bvec, float* __restrict__ bnsum,
                        float* __restrict__ bnsumsq) {
    if (blockIdx.x == 64) {
        int t = threadIdx.x;
        if (t < 128) {
            bnsum[t] = 0.0f;
            float acc = 0.0f;
            for (int d = 0; d < 128; d++) acc += vsum[d] * W0[d * 128 + t];
            bvec[t] = acc;
        } else {
            bnsumsq[t - 128] = 0.0f;
        }
        return;
    }
    int idx = blockIdx.x * 256 + threadIdx.x;
    int m = idx >> 7;
    int c = idx & 127;
    float acc = 0.0f;
    for (int d = 0; d < 128; d += 4) {
        float4 k4 = *(const float4*)(kvs + m * 128 + d);
        acc += k4.x * W0[(d + 0) * 128 + c] + k4.y * W0[(d + 1) * 128 + c] +
               k4.z * W0[(d + 2) * 128 + c] + k4.w * W0[(d + 3) * 128 + c];
    }
    int t = c >> 4, l16 = c & 15, kc = m >> 5, quad = (m >> 3) & 3, j = m & 7;
    int lane = quad * 16 + l16;
    WpM1[(size_t)(((t * 4 + kc) * 64) + lane) * 8 + j] = (bf16_t)acc;
}

// ---------------- BN apply (finalize fused per block) ----------------
__global__ void bn_apply2(const bf16_t* __restrict__ z, bf16_t* __restrict__ hb,
                          const float* __restrict__ sums, const float* __restrict__ sumsq,
                          const float* __restrict__ g, const float* __restrict__ bb, int n4) {
    __shared__ float sc[128], sh[128];
    int t = threadIdx.x;
    if (t < 128) {
        float m = sums[t] / (float)NN;
        float var = sumsq[t] / (float)NN - m * m;
        float s = g[t] * rsqrtf(var + EPS_BN);
        sc[t] = s;
        sh[t] = bb[t] - m * s;
    }
    __syncthreads();
    int i = blockIdx.x * 256 + t;
    if (i >= n4) return;
    int c4 = (i & 31) * 4;
    bf16x4 zv = *(const bf16x4*)(z + (size_t)i * 4);
    bf16x4 o;
    #pragma unroll
    for (int j = 0; j < 4; j++)
        o[j] = (bf16_t)fmaxf((float)zv[j] * sc[c4 + j] + sh[c4 + j], 0.0f);
    *(bf16x4*)(hb + (size_t)i * 4) = o;
}

extern "C" void kernel_launch(void* const* d_in, const int* in_sizes, int n_in,
                              void* d_out, int out_size, void* d_ws, size_t ws_size,
                              hipStream_t stream) {
    const float* x = (const float*)d_in[0];
    const int* eidx = (const int*)d_in[1];
    const float* W_in = (const float*)d_in[2];
    const float* b_in = (const float*)d_in[3];
    const float* Wq = (const float*)d_in[4];
    const float* bq = (const float*)d_in[5];
    const float* Wk = (const float*)d_in[6];
    const float* bk = (const float*)d_in[7];
    const float* Wfc = (const float*)d_in[8];
    const float* bfc = (const float*)d_in[9];
    const float* W_out = (const float*)d_in[10];
    const float* b_out = (const float*)d_in[11];
    const float* bn_g = (const float*)d_in[12];
    const float* bn_b = (const float*)d_in[13];
    float* out = (float*)d_out;

    const int N = NN, E = NE;
    const int* rowp = eidx;
    const int* colp = eidx + E;

    char* ws = (char*)d_ws;
    size_t off = 0;
    auto nxt = [&](size_t bytes) -> void* {
        void* p = ws + off;
        off += (bytes + 255) & ~(size_t)255;
        return p;
    };
    int* counts = (int*)nxt((size_t)N * 4);
    int* cursor = (int*)nxt((size_t)N * 4);  // adjacent to counts: one memset covers both
    int* offsets = (int*)nxt((size_t)(N + 1) * 4);
    int* bsum = (int*)nxt(1024);
    int2* edges = (int2*)nxt((size_t)E * 8);
    float* dis = (float*)nxt((size_t)N * 4);
    float* den = (float*)nxt((size_t)N * 4);
    float* kvs = (float*)nxt((size_t)HD * HD * 4);  // + ksum + vsum contiguous
    float* ksum = (float*)nxt((size_t)HD * 4);
    float* vsum = (float*)nxt((size_t)HD * 4);
    float* bnsum = (float*)nxt((size_t)HD * 4);
    float* bnsumsq = (float*)nxt((size_t)HD * 4);
    float* bvec = (float*)nxt((size_t)HD * 4);
    // bf16 activations
    bf16_t* zb = (bf16_t*)nxt((size_t)N * HD * 2);
    bf16_t* hb = (bf16_t*)nxt((size_t)N * HD * 2);
    bf16_t* p1b = (bf16_t*)nxt((size_t)N * HD * 2);
    bf16_t* p2b = (bf16_t*)nxt((size_t)N * HD * 2);
    bf16_t* p3b = (bf16_t*)nxt((size_t)N * HD * 2);
    bf16_t* knb = (bf16_t*)nxt((size_t)N * HD * 2);
    bf16_t* qnb = (bf16_t*)nxt((size_t)N * HD * 2);
    // fragment-packed bf16 weights
    bf16_t* Wp_in = (bf16_t*)nxt((size_t)8 * 4 * 64 * 8 * 2);
    bf16_t* Wp_q = (bf16_t*)nxt((size_t)2 * 8 * 4 * 64 * 8 * 2);
    bf16_t* Wp_k = (bf16_t*)nxt((size_t)2 * 8 * 4 * 64 * 8 * 2);
    bf16_t* Wp_fc = (bf16_t*)nxt((size_t)2 * 8 * 20 * 64 * 8 * 2);
    bf16_t* WpM1 = (bf16_t*)nxt((size_t)8 * 4 * 64 * 8 * 2);
    bf16_t* Wp_out = (bf16_t*)nxt((size_t)3 * 4 * 64 * 8 * 2);

    const int GB = (N + 63) / 64;
    const int GB2 = (N + 127) / 128;
    const int QSZ = HD * HD;
    const int FSZ = 8 * 20 * 64 * 8;
    const int NB = (N + 255) / 256;

    // ---- CSR build ----
    hipMemsetAsync(counts, 0, (size_t)2 * ((N * 4 + 255) & ~255), stream);
    count_edges<<<(E + 255) / 256, 256, 0, stream>>>(colp, counts, E);
    scan1<<<NB, 256, 0, stream>>>(counts, offsets, bsum, dis, N);
    scan2<<<1, 256, 0, stream>>>(bsum, offsets, NB, N);
    scan3<<<NB, 256, 0, stream>>>(offsets, bsum, N);
    scatter_edges2<<<(E + 255) / 256, 256, 0, stream>>>(rowp, colp, dis, offsets, cursor,
                                                        edges, E);

    // ---- all weight packing + zero BN stats (one launch) ----
    wcvt_all<<<124, 256, 0, stream>>>(W_in, Wq, Wk, Wfc, W_out, Wp_in, Wp_q, Wp_k, Wp_fc,
                                      Wp_out, bnsum, bnsumsq);

    // ---- input layer (fused BN stats) ----
    gemm128s<float, false><<<GB, 256, 0, stream>>>(x, Wp_in, b_in, nullptr, nullptr, bnsum,
                                                   bnsumsq, nullptr, 0, nullptr, zb, N);
    bn_apply2<<<(N * 32 + 255) / 256, 256, 0, stream>>>(zb, hb, bnsum, bnsumsq, bn_g, bn_b,
                                                        N * 32);

    for (int i = 0; i < 2; i++) {
        const float* bq_i = bq + (size_t)i * HD;
        const float* bk_i = bk + (size_t)i * HD;
        const float* bfc_i = bfc + (size_t)i * HD;
        const float* Wfc_i = Wfc + (size_t)i * 640 * HD;  // rows 0..127 = W0
        bf16_t* Wp_q_i = Wp_q + (size_t)i * QSZ;
        bf16_t* Wp_k_i = Wp_k + (size_t)i * QSZ;
        bf16_t* Wp_fc_i = Wp_fc + (size_t)i * FSZ;

        // K-hop diffusion (bf16)
        prop_b3<<<(N + 3) / 4, 256, 0, stream>>>(offsets, edges, hb, p1b);
        prop_b3<<<(N + 3) / 4, 256, 0, stream>>>(offsets, edges, p1b, p2b);
        prop_b3<<<(N + 3) / 4, 256, 0, stream>>>(offsets, edges, p2b, p3b);

        // attention: k-gemm (also zeroes kvs+ksum+vsum), kvs, q-gemm (fused den)
        gemm128s<bf16_t, true><<<GB, 256, 0, stream>>>(hb, Wp_k_i, bk_i, nullptr, nullptr,
                                                       nullptr, nullptr, kvs, HD * HD + 2 * HD,
                                                       nullptr, knb, N);
        kvs_mfma<<<256, 256, 0, stream>>>(knb, hb, kvs, ksum, vsum, N);
        gemm128s<bf16_t, true><<<GB, 256, 0, stream>>>(hb, Wp_q_i, bq_i, ksum, den, nullptr,
                                                       nullptr, nullptr, 0, nullptr, qnb, N);
        m1_pack<<<65, 256, 0, stream>>>(kvs, Wfc_i, vsum, WpM1, bvec, bnsum, bnsumsq);

        // z = qn@M1 + dinv*bvec + [h,p1,p2,p3]@W[128:] + bfc + hb  (fused BN stats)
        gemm_fc<<<GB2, 256, 0, stream>>>(qnb, hb, p1b, p2b, p3b, WpM1, Wp_fc_i, bvec, bfc_i,
                                         den, hb, bnsum, bnsumsq, zb, N);
        bn_apply2<<<(N * 32 + 255) / 256, 256, 0, stream>>>(zb, hb, bnsum, bnsumsq,
                                                            bn_g + (size_t)(i + 1) * HD,
                                                            bn_b + (size_t)(i + 1) * HD,
                                                            N * 32);
    }

    out_mfma<<<GB, 256, 0, stream>>>(hb, Wp_out, b_out, out, N);
}

// Round 12
// 611.435 us; speedup vs baseline: 1.1424x; 1.0066x over previous
//
#include <hip/hip_runtime.h>
#include <hip/hip_bf16.h>
#include <hip/hip_fp16.h>
#include <math.h>

#define NN 50000
#define NE 800000
#define HD 128
#define EPS_BN 1e-5f

typedef __bf16 bf16_t;
typedef bf16_t bf16x8 __attribute__((ext_vector_type(8)));
typedef bf16_t bf16x4 __attribute__((ext_vector_type(4)));
typedef float f32x4 __attribute__((ext_vector_type(4)));

// ---------------- CSR build ----------------
__global__ void count_edges(const int* __restrict__ col, int* __restrict__ counts, int E) {
    int e = blockIdx.x * 256 + threadIdx.x;
    if (e >= E) return;
    atomicAdd(&counts[col[e]], 1);
}

// scan1 + dis fused
__global__ __launch_bounds__(256) void scan1(const int* __restrict__ counts,
                                             int* __restrict__ offsets,
                                             int* __restrict__ bsum,
                                             float* __restrict__ dis, int n) {
    __shared__ int wsl[4];
    int t = threadIdx.x, lane = t & 63, w = t >> 6;
    int i = blockIdx.x * 256 + t;
    int v = (i < n) ? counts[i] : 0;
    if (i < n) dis[i] = (v > 0) ? rsqrtf((float)v) : 0.0f;
    int x = v;
    #pragma unroll
    for (int o = 1; o < 64; o <<= 1) {
        int tt = __shfl_up(x, o, 64);
        if (lane >= o) x += tt;
    }
    if (lane == 63) wsl[w] = x;
    __syncthreads();
    if (t == 0) {
        int s = 0;
        #pragma unroll
        for (int k = 0; k < 4; k++) { int tmp = wsl[k]; wsl[k] = s; s += tmp; }
        bsum[blockIdx.x] = s;
    }
    __syncthreads();
    if (i < n) offsets[i] = x - v + wsl[w];
}

__global__ __launch_bounds__(256) void scan2(int* __restrict__ bsum, int* __restrict__ offsets,
                                             int nb, int n) {
    __shared__ int wsl[4];
    int t = threadIdx.x, lane = t & 63, w = t >> 6;
    int v = (t < nb) ? bsum[t] : 0;
    int x = v;
    #pragma unroll
    for (int o = 1; o < 64; o <<= 1) {
        int tt = __shfl_up(x, o, 64);
        if (lane >= o) x += tt;
    }
    if (lane == 63) wsl[w] = x;
    __syncthreads();
    if (t == 0) {
        int s = 0;
        #pragma unroll
        for (int k = 0; k < 4; k++) { int tmp = wsl[k]; wsl[k] = s; s += tmp; }
    }
    __syncthreads();
    int excl = x - v + wsl[w];
    if (t < nb) bsum[t] = excl;
    if (t == nb - 1) offsets[n] = excl + v;
}

__global__ void scan3(int* __restrict__ offsets, const int* __restrict__ bsum, int n) {
    int i = blockIdx.x * 256 + threadIdx.x;
    if (i < n) offsets[i] += bsum[blockIdx.x];
}

// 4-byte edge record: row (low 16) | fp16 weight (high 16). N=50000 < 65536.
__global__ void scatter_edges3(const int* __restrict__ row, const int* __restrict__ col,
                               const float* __restrict__ dis, const int* __restrict__ offsets,
                               int* __restrict__ cursor, unsigned int* __restrict__ edges,
                               int E) {
    int e = blockIdx.x * 256 + threadIdx.x;
    if (e >= E) return;
    int c = col[e], r = row[e];
    int pos = offsets[c] + atomicAdd(&cursor[c], 1);
    unsigned short hw = __half_as_ushort(__float2half(dis[c] * dis[r]));
    edges[pos] = (unsigned int)r | ((unsigned int)hw << 16);
}

// ---------------- Graph propagation: 1 wave/node, 4 quarters x 16B lanes, 2-edge unroll ----------------
__global__ __launch_bounds__(256) void prop_b3(const int* __restrict__ offsets,
                                               const unsigned int* __restrict__ edges,
                                               const bf16_t* __restrict__ in,
                                               bf16_t* __restrict__ out) {
    int wave = threadIdx.x >> 6;
    int lane = threadIdx.x & 63;
    int q = lane >> 4;          // quarter 0..3
    int ch8 = (lane & 15) * 8;  // 8 channels per lane
    int c = blockIdx.x * 4 + wave;
    if (c >= NN) return;
    int s = offsets[c], e = offsets[c + 1];
    float a[8] = {};
    int i = s + q;
    for (; i + 4 < e; i += 8) {  // 2 edges per quarter per iter
        unsigned int r0 = edges[i], r1 = edges[i + 4];
        bf16x8 v0 = *(const bf16x8*)(in + ((size_t)(r0 & 0xFFFFu) << 7) + ch8);
        bf16x8 v1 = *(const bf16x8*)(in + ((size_t)(r1 & 0xFFFFu) << 7) + ch8);
        float w0 = __half2float(__ushort_as_half((unsigned short)(r0 >> 16)));
        float w1 = __half2float(__ushort_as_half((unsigned short)(r1 >> 16)));
        #pragma unroll
        for (int j = 0; j < 8; j++) a[j] += w0 * (float)v0[j] + w1 * (float)v1[j];
    }
    for (; i < e; i += 4) {
        unsigned int r0 = edges[i];
        bf16x8 v0 = *(const bf16x8*)(in + ((size_t)(r0 & 0xFFFFu) << 7) + ch8);
        float w0 = __half2float(__ushort_as_half((unsigned short)(r0 >> 16)));
        #pragma unroll
        for (int j = 0; j < 8; j++) a[j] += w0 * (float)v0[j];
    }
    #pragma unroll
    for (int j = 0; j < 8; j++) {
        a[j] += __shfl_xor(a[j], 16);
        a[j] += __shfl_xor(a[j], 32);
    }
    if (q == 0) {
        bf16x8 o;
        #pragma unroll
        for (int j = 0; j < 8; j++) o[j] = (bf16_t)a[j];
        *(bf16x8*)(out + ((size_t)c << 7) + ch8) = o;
    }
}

// ---------------- Mega weight-pack kernel ----------------
__device__ inline void pack_frag(const float* __restrict__ W, bf16_t* __restrict__ Wp, int nkc,
                                 int lb) {
    int p = lb * 256 + threadIdx.x;
    if (p >= 8 * nkc * 64) return;
    int lane = p & 63;
    int tk = p >> 6;
    int kc = tk % nkc;
    int t = tk / nkc;
    int n = t * 16 + (lane & 15);
    int k0 = kc * 32 + (lane >> 4) * 8;
    bf16x8 f;
    #pragma unroll
    for (int j = 0; j < 8; j++) f[j] = (bf16_t)W[(size_t)(k0 + j) * 128 + n];
    *(bf16x8*)(Wp + (size_t)p * 8) = f;
}

__global__ void wcvt_all(const float* __restrict__ W_in, const float* __restrict__ Wq,
                         const float* __restrict__ Wk, const float* __restrict__ Wfc,
                         const float* __restrict__ W_out, bf16_t* __restrict__ Wp_in,
                         bf16_t* __restrict__ Wp_q, bf16_t* __restrict__ Wp_k,
                         bf16_t* __restrict__ Wp_fc, bf16_t* __restrict__ Wp_out,
                         float* __restrict__ bnsum, float* __restrict__ bnsumsq) {
    const int QSZ = HD * HD;
    const int FSZ = 8 * 20 * 64 * 8;
    int b = blockIdx.x;
    if (b < 8) { pack_frag(W_in, Wp_in, 4, b); return; }
    if (b < 16) { pack_frag(Wq, Wp_q, 4, b - 8); return; }
    if (b < 24) { pack_frag(Wq + QSZ, Wp_q + QSZ, 4, b - 16); return; }
    if (b < 32) { pack_frag(Wk, Wp_k, 4, b - 24); return; }
    if (b < 40) { pack_frag(Wk + QSZ, Wp_k + QSZ, 4, b - 32); return; }
    if (b < 80) { pack_frag(Wfc, Wp_fc, 20, b - 40); return; }
    if (b < 120) { pack_frag(Wfc + 640 * HD, Wp_fc + FSZ, 20, b - 80); return; }
    if (b < 123) {  // W_out [128][40] -> 3 tiles padded to 48
        int p = (b - 120) * 256 + threadIdx.x;
        if (p >= 3 * 4 * 64) return;
        int lane = p & 63;
        int tk = p >> 6;
        int kc = tk & 3;
        int t = tk >> 2;
        int n = t * 16 + (lane & 15);
        int k0 = kc * 32 + (lane >> 4) * 8;
        bf16x8 f;
        #pragma unroll
        for (int j = 0; j < 8; j++)
            f[j] = (n < 40) ? (bf16_t)W_out[(size_t)(k0 + j) * 40 + n] : (bf16_t)0.0f;
        *(bf16x8*)(Wp_out + (size_t)p * 8) = f;
        return;
    }
    int t = threadIdx.x;
    if (t < 128) bnsum[t] = 0.0f;
    else bnsumsq[t - 128] = 0.0f;
}

// ---------------- A-fragment loaders ----------------
__device__ inline bf16x8 loadA(const float* ap) {
    float4 a0 = *(const float4*)ap;
    float4 a1 = *(const float4*)(ap + 4);
    bf16x8 f;
    f[0] = (bf16_t)a0.x; f[1] = (bf16_t)a0.y; f[2] = (bf16_t)a0.z; f[3] = (bf16_t)a0.w;
    f[4] = (bf16_t)a1.x; f[5] = (bf16_t)a1.y; f[6] = (bf16_t)a1.z; f[7] = (bf16_t)a1.w;
    return f;
}
__device__ inline bf16x8 loadA(const bf16_t* ap) { return *(const bf16x8*)ap; }

// ---------------- MFMA GEMM (K=128): batched A-loads; norm / den+scale / bn-stats / zero-buf ----------------
template <typename T, bool NORM>
__global__ __launch_bounds__(256) void gemm128s(const T* __restrict__ A,
                                                const bf16_t* __restrict__ Wp,
                                                const float* __restrict__ bias,
                                                const float* __restrict__ ksum_p,
                                                float* __restrict__ den_out,
                                                float* __restrict__ sums,
                                                float* __restrict__ sumsq,
                                                float* __restrict__ zero_buf, int zero_len,
                                                float* __restrict__ out,
                                                bf16_t* __restrict__ outb, int N) {
    __shared__ float lsum[128], lsq[128];
    int tid = threadIdx.x;
    if (zero_buf && blockIdx.x < 17) {  // zero kvs+ksum+vsum for the next kernel
        int base = (blockIdx.x * 256 + tid) * 4;
        if (base < zero_len) *(float4*)(zero_buf + base) = make_float4(0.f, 0.f, 0.f, 0.f);
    }
    int wave = tid >> 6;
    int lane = tid & 63;
    int quad = lane >> 4;
    int l16 = lane & 15;
    int m0 = blockIdx.x * 64 + wave * 16;
    int arow = m0 + l16;

    bf16x8 afr[4];
    if (arow < N) {
        #pragma unroll
        for (int kc = 0; kc < 4; kc++)
            afr[kc] = loadA(A + ((size_t)arow << 7) + kc * 32 + quad * 8);
    } else {
        #pragma unroll
        for (int kc = 0; kc < 4; kc++) afr[kc] = (bf16x8){};
    }

    f32x4 acc[8] = {};
    #pragma unroll
    for (int kc = 0; kc < 4; kc++) {
        bf16x8 bfr[8];
        #pragma unroll
        for (int t = 0; t < 8; t++)
            bfr[t] = *(const bf16x8*)(Wp + (size_t)(((t * 4 + kc) * 64) + lane) * 8);
        #pragma unroll
        for (int t = 0; t < 8; t++)
            acc[t] = __builtin_amdgcn_mfma_f32_16x16x32_bf16(afr[kc], bfr[t], acc[t], 0, 0, 0);
    }
    float vals[8][4];
    #pragma unroll
    for (int t = 0; t < 8; t++) {
        float b = bias ? bias[t * 16 + l16] : 0.0f;
        #pragma unroll
        for (int r = 0; r < 4; r++) vals[t][r] = acc[t][r] + b;
    }
    if (NORM) {
        #pragma unroll
        for (int r = 0; r < 4; r++) {
            float p = 0.0f;
            #pragma unroll
            for (int t = 0; t < 8; t++) p += vals[t][r] * vals[t][r];
            p += __shfl_xor(p, 1);
            p += __shfl_xor(p, 2);
            p += __shfl_xor(p, 4);
            p += __shfl_xor(p, 8);
            float inv = rsqrtf(p);
            #pragma unroll
            for (int t = 0; t < 8; t++) vals[t][r] *= inv;
        }
    }
    if (ksum_p) {  // fused den = qn . ksum + N; scale row by 1/den
        float kv[8];
        #pragma unroll
        for (int t = 0; t < 8; t++) kv[t] = ksum_p[t * 16 + l16];
        #pragma unroll
        for (int r = 0; r < 4; r++) {
            float dp = 0.0f;
            #pragma unroll
            for (int t = 0; t < 8; t++) dp += vals[t][r] * kv[t];
            dp += __shfl_xor(dp, 1);
            dp += __shfl_xor(dp, 2);
            dp += __shfl_xor(dp, 4);
            dp += __shfl_xor(dp, 8);
            float dv = dp + (float)NN;
            int rr = m0 + quad * 4 + r;
            if (l16 == 0 && rr < N) den_out[rr] = dv;
            float dinv = 1.0f / dv;
            #pragma unroll
            for (int t = 0; t < 8; t++) vals[t][r] *= dinv;
        }
    }
    #pragma unroll
    for (int r = 0; r < 4; r++) {
        int rr = m0 + quad * 4 + r;
        if (rr >= N) continue;
        #pragma unroll
        for (int t = 0; t < 8; t++) {
            int c = t * 16 + l16;
            float v = vals[t][r];
            if (out) out[((size_t)rr << 7) + c] = v;
            if (outb) outb[((size_t)rr << 7) + c] = (bf16_t)v;
        }
    }
    if (sums) {  // fused BN stats
        if (tid < 128) { lsum[tid] = 0.0f; lsq[tid] = 0.0f; }
        __syncthreads();
        float sp[8] = {}, qp[8] = {};
        #pragma unroll
        for (int r = 0; r < 4; r++) {
            int rr = m0 + quad * 4 + r;
            if (rr >= N) continue;
            #pragma unroll
            for (int t = 0; t < 8; t++) {
                float v = vals[t][r];
                sp[t] += v;
                qp[t] += v * v;
            }
        }
        #pragma unroll
        for (int t = 0; t < 8; t++) {
            sp[t] += __shfl_xor(sp[t], 16);
            sp[t] += __shfl_xor(sp[t], 32);
            qp[t] += __shfl_xor(qp[t], 16);
            qp[t] += __shfl_xor(qp[t], 32);
        }
        if (quad == 0) {
            #pragma unroll
            for (int t = 0; t < 8; t++) {
                atomicAdd(&lsum[t * 16 + l16], sp[t]);
                atomicAdd(&lsq[t * 16 + l16], qp[t]);
            }
        }
        __syncthreads();
        if (tid < 128) {
            atomicAdd(&sums[tid], lsum[tid]);
            atomicAdd(&sumsq[tid], lsq[tid]);
        }
    }
}

// ---------------- fc GEMM: single 640-K loop, 2 m-tiles/wave, fused BN stats ----------------
__global__ __launch_bounds__(256, 1) void gemm_fc(
    const bf16_t* __restrict__ qn, const bf16_t* __restrict__ s1, const bf16_t* __restrict__ s2,
    const bf16_t* __restrict__ s3, const bf16_t* __restrict__ s4,
    const bf16_t* __restrict__ WpM1, const bf16_t* __restrict__ Wp,
    const float* __restrict__ bvec, const float* __restrict__ bfc,
    const float* __restrict__ den, const bf16_t* __restrict__ resb,
    float* __restrict__ sums, float* __restrict__ sumsq,
    bf16_t* __restrict__ outb, int N) {
    __shared__ float lsum[128], lsq[128];
    const bf16_t* srcs[5] = {qn, s1, s2, s3, s4};
    int tid = threadIdx.x;
    int wave = tid >> 6;
    int lane = tid & 63;
    int quad = lane >> 4;
    int l16 = lane & 15;
    int m0 = blockIdx.x * 128 + wave * 32;  // 2 m-tiles per wave

    f32x4 acc[2][8] = {};
    #pragma unroll
    for (int kc = 0; kc < 20; kc++) {
        int s = kc >> 2;
        int klocal = (kc & 3) * 32;
        bf16x8 bfr[8];
        #pragma unroll
        for (int t = 0; t < 8; t++) {
            const bf16_t* bp = (kc < 4) ? WpM1 + (size_t)(((t * 4 + kc) * 64) + lane) * 8
                                        : Wp + (size_t)(((t * 20 + kc) * 64) + lane) * 8;
            bfr[t] = *(const bf16x8*)bp;
        }
        bf16x8 af[2] = {};
        #pragma unroll
        for (int m = 0; m < 2; m++) {
            int arow = m0 + m * 16 + l16;
            if (arow < N)
                af[m] = *(const bf16x8*)(srcs[s] + ((size_t)arow << 7) + klocal + quad * 8);
        }
        #pragma unroll
        for (int t = 0; t < 8; t++) {
            #pragma unroll
            for (int m = 0; m < 2; m++)
                acc[m][t] = __builtin_amdgcn_mfma_f32_16x16x32_bf16(af[m], bfr[t], acc[m][t],
                                                                    0, 0, 0);
        }
    }
    float bv[8], bf[8];
    #pragma unroll
    for (int t = 0; t < 8; t++) {
        bv[t] = bvec[t * 16 + l16];
        bf[t] = bfc[t * 16 + l16];
    }
    if (tid < 128) { lsum[tid] = 0.0f; lsq[tid] = 0.0f; }
    __syncthreads();
    float sp[8] = {}, qp[8] = {};
    #pragma unroll
    for (int m = 0; m < 2; m++) {
        #pragma unroll
        for (int r = 0; r < 4; r++) {
            int rr = m0 + m * 16 + quad * 4 + r;
            if (rr >= N) continue;
            float dinv = 1.0f / den[rr];
            #pragma unroll
            for (int t = 0; t < 8; t++) {
                int c = t * 16 + l16;
                float v = acc[m][t][r] + dinv * bv[t] + bf[t] +
                          (float)resb[((size_t)rr << 7) + c];
                outb[((size_t)rr << 7) + c] = (bf16_t)v;
                sp[t] += v;
                qp[t] += v * v;
            }
        }
    }
    #pragma unroll
    for (int t = 0; t < 8; t++) {
        sp[t] += __shfl_xor(sp[t], 16);
        sp[t] += __shfl_xor(sp[t], 32);
        qp[t] += __shfl_xor(qp[t], 16);
        qp[t] += __shfl_xor(qp[t], 32);
    }
    if (quad == 0) {
        #pragma unroll
        for (int t = 0; t < 8; t++) {
            atomicAdd(&lsum[t * 16 + l16], sp[t]);
            atomicAdd(&lsq[t * 16 + l16], qp[t]);
        }
    }
    __syncthreads();
    if (tid < 128) {
        atomicAdd(&sums[tid], lsum[tid]);
        atomicAdd(&sumsq[tid], lsq[tid]);
    }
}

// ---------------- out GEMM via MFMA ----------------
__global__ __launch_bounds__(256) void out_mfma(const bf16_t* __restrict__ hb,
                                                const bf16_t* __restrict__ Wp,
                                                const float* __restrict__ bias,
                                                float* __restrict__ out, int N) {
    int wave = threadIdx.x >> 6;
    int lane = threadIdx.x & 63;
    int quad = lane >> 4;
    int l16 = lane & 15;
    int m0 = blockIdx.x * 64 + wave * 16;
    int arow = m0 + l16;

    bf16x8 afr[4];
    if (arow < N) {
        #pragma unroll
        for (int kc = 0; kc < 4; kc++)
            afr[kc] = *(const bf16x8*)(hb + ((size_t)arow << 7) + kc * 32 + quad * 8);
    } else {
        #pragma unroll
        for (int kc = 0; kc < 4; kc++) afr[kc] = (bf16x8){};
    }
    f32x4 acc[3] = {};
    #pragma unroll
    for (int kc = 0; kc < 4; kc++) {
        #pragma unroll
        for (int t = 0; t < 3; t++) {
            const bf16_t* bp = Wp + (size_t)(((t * 4 + kc) * 64) + lane) * 8;
            acc[t] = __builtin_amdgcn_mfma_f32_16x16x32_bf16(afr[kc], *(const bf16x8*)bp,
                                                             acc[t], 0, 0, 0);
        }
    }
    #pragma unroll
    for (int r = 0; r < 4; r++) {
        int rr = m0 + quad * 4 + r;
        if (rr >= N) continue;
        #pragma unroll
        for (int t = 0; t < 3; t++) {
            int c = t * 16 + l16;
            if (c < 40) out[(size_t)rr * 40 + c] = acc[t][r] + bias[c];
        }
    }
}

// ---------------- kvs via MFMA ----------------
__global__ __launch_bounds__(256) void kvs_mfma(const bf16_t* __restrict__ kn,
                                                const bf16_t* __restrict__ v,
                                                float* __restrict__ kvs,
                                                float* __restrict__ ksum,
                                                float* __restrict__ vsum, int N) {
    __shared__ bf16_t Lk[32][132];
    __shared__ bf16_t Lv[32][132];
    __shared__ float lred[256];
    int t = threadIdx.x;
    int wave = t >> 6, lane = t & 63, quad = lane >> 4, l16 = lane & 15;
    int tr = t >> 4, tc = (t & 15) * 8;
    int mbase = wave * 32;
    f32x4 acc[2][8] = {};
    float ks[8] = {}, vs[8] = {};
    for (int base = blockIdx.x * 32; base < N; base += gridDim.x * 32) {
        __syncthreads();
        #pragma unroll
        for (int hh = 0; hh < 2; hh++) {
            int r = hh * 16 + tr;
            int rowi = base + r;
            bf16x8 ck = {}, cv = {};
            if (rowi < N) {
                ck = *(const bf16x8*)(kn + ((size_t)rowi << 7) + tc);
                cv = *(const bf16x8*)(v + ((size_t)rowi << 7) + tc);
            }
            bf16x4 klo, khi, vlo, vhi;
            #pragma unroll
            for (int j = 0; j < 4; j++) {
                klo[j] = ck[j]; khi[j] = ck[j + 4];
                vlo[j] = cv[j]; vhi[j] = cv[j + 4];
                ks[j] += (float)ck[j]; ks[j + 4] += (float)ck[j + 4];
                vs[j] += (float)cv[j]; vs[j + 4] += (float)cv[j + 4];
            }
            *(bf16x4*)&Lk[r][tc] = klo;
            *(bf16x4*)&Lk[r][tc + 4] = khi;
            *(bf16x4*)&Lv[r][tc] = vlo;
            *(bf16x4*)&Lv[r][tc + 4] = vhi;
        }
        __syncthreads();
        bf16x8 af[2], bfr[8];
        #pragma unroll
        for (int mt = 0; mt < 2; mt++)
            #pragma unroll
            for (int j = 0; j < 8; j++) af[mt][j] = Lk[quad * 8 + j][mbase + mt * 16 + l16];
        #pragma unroll
        for (int tt = 0; tt < 8; tt++)
            #pragma unroll
            for (int j = 0; j < 8; j++) bfr[tt][j] = Lv[quad * 8 + j][tt * 16 + l16];
        #pragma unroll
        for (int mt = 0; mt < 2; mt++)
            #pragma unroll
            for (int tt = 0; tt < 8; tt++)
                acc[mt][tt] = __builtin_amdgcn_mfma_f32_16x16x32_bf16(af[mt], bfr[tt],
                                                                      acc[mt][tt], 0, 0, 0);
    }
    #pragma unroll
    for (int mt = 0; mt < 2; mt++)
        #pragma unroll
        for (int tt = 0; tt < 8; tt++)
            #pragma unroll
            for (int r = 0; r < 4; r++) {
                int m = mbase + mt * 16 + quad * 4 + r;
                int d = tt * 16 + l16;
                atomicAdd(&kvs[m * HD + d], acc[mt][tt][r]);
            }
    lred[t] = 0.0f;
    __syncthreads();
    #pragma unroll
    for (int j = 0; j < 8; j++) {
        atomicAdd(&lred[tc + j], ks[j]);
        atomicAdd(&lred[128 + tc + j], vs[j]);
    }
    __syncthreads();
    if (t < 128) {
        atomicAdd(&ksum[t], lred[t]);
        atomicAdd(&vsum[t], lred[t + 128]);
    }
}

// ---------------- M1 = kvs @ W0 (frag-packed), bvec = vsum @ W0, zero BN stats ----------------
__global__ void m1_pack(const float* __restrict__ kvs, const float* __restrict__ W0,
                        const float* __restrict__ vsum, bf16_t* __restrict__ WpM1,
                        float* __restrict__ bvec, float* __restrict__ bnsum,
                        float* __restrict__ bnsumsq) {
    if (blockIdx.x == 64) {
        int t = threadIdx.x;
        if (t < 128) {
            bnsum[t] = 0.0f;
            float acc = 0.0f;
            for (int d = 0; d < 128; d++) acc += vsum[d] * W0[d * 128 + t];
            bvec[t] = acc;
        } else {
            bnsumsq[t - 128] = 0.0f;
        }
        return;
    }
    int idx = blockIdx.x * 256 + threadIdx.x;
    int m = idx >> 7;
    int c = idx & 127;
    float acc = 0.0f;
    for (int d = 0; d < 128; d += 4) {
        float4 k4 = *(const float4*)(kvs + m * 128 + d);
        acc += k4.x * W0[(d + 0) * 128 + c] + k4.y * W0[(d + 1) * 128 + c] +
               k4.z * W0[(d + 2) * 128 + c] + k4.w * W0[(d + 3) * 128 + c];
    }
    int t = c >> 4, l16 = c & 15, kc = m >> 5, quad = (m >> 3) & 3, j = m & 7;
    int lane = quad * 16 + l16;
    WpM1[(size_t)(((t * 4 + kc) * 64) + lane) * 8 + j] = (bf16_t)acc;
}

// ---------------- BN apply (finalize fused per block) ----------------
__global__ void bn_apply2(const bf16_t* __restrict__ z, bf16_t* __restrict__ hb,
                          const float* __restrict__ sums, const float* __restrict__ sumsq,
                          const float* __restrict__ g, const float* __restrict__ bb, int n4) {
    __shared__ float sc[128], sh[128];
    int t = threadIdx.x;
    if (t < 128) {
        float m = sums[t] / (float)NN;
        float var = sumsq[t] / (float)NN - m * m;
        float s = g[t] * rsqrtf(var + EPS_BN);
        sc[t] = s;
        sh[t] = bb[t] - m * s;
    }
    __syncthreads();
    int i = blockIdx.x * 256 + t;
    if (i >= n4) return;
    int c4 = (i & 31) * 4;
    bf16x4 zv = *(const bf16x4*)(z + (size_t)i * 4);
    bf16x4 o;
    #pragma unroll
    for (int j = 0; j < 4; j++)
        o[j] = (bf16_t)fmaxf((float)zv[j] * sc[c4 + j] + sh[c4 + j], 0.0f);
    *(bf16x4*)(hb + (size_t)i * 4) = o;
}

extern "C" void kernel_launch(void* const* d_in, const int* in_sizes, int n_in,
                              void* d_out, int out_size, void* d_ws, size_t ws_size,
                              hipStream_t stream) {
    const float* x = (const float*)d_in[0];
    const int* eidx = (const int*)d_in[1];
    const float* W_in = (const float*)d_in[2];
    const float* b_in = (const float*)d_in[3];
    const float* Wq = (const float*)d_in[4];
    const float* bq = (const float*)d_in[5];
    const float* Wk = (const float*)d_in[6];
    const float* bk = (const float*)d_in[7];
    const float* Wfc = (const float*)d_in[8];
    const float* bfc = (const float*)d_in[9];
    const float* W_out = (const float*)d_in[10];
    const float* b_out = (const float*)d_in[11];
    const float* bn_g = (const float*)d_in[12];
    const float* bn_b = (const float*)d_in[13];
    float* out = (float*)d_out;

    const int N = NN, E = NE;
    const int* rowp = eidx;
    const int* colp = eidx + E;

    char* ws = (char*)d_ws;
    size_t off = 0;
    auto nxt = [&](size_t bytes) -> void* {
        void* p = ws + off;
        off += (bytes + 255) & ~(size_t)255;
        return p;
    };
    int* counts = (int*)nxt((size_t)N * 4);
    int* cursor = (int*)nxt((size_t)N * 4);  // adjacent to counts: one memset covers both
    int* offsets = (int*)nxt((size_t)(N + 1) * 4);
    int* bsum = (int*)nxt(1024);
    unsigned int* edges = (unsigned int*)nxt((size_t)E * 4);
    float* dis = (float*)nxt((size_t)N * 4);
    float* den = (float*)nxt((size_t)N * 4);
    float* kvs = (float*)nxt((size_t)HD * HD * 4);  // + ksum + vsum contiguous
    float* ksum = (float*)nxt((size_t)HD * 4);
    float* vsum = (float*)nxt((size_t)HD * 4);
    float* bnsum = (float*)nxt((size_t)HD * 4);
    float* bnsumsq = (float*)nxt((size_t)HD * 4);
    float* bvec = (float*)nxt((size_t)HD * 4);
    // bf16 activations
    bf16_t* zb = (bf16_t*)nxt((size_t)N * HD * 2);
    bf16_t* hb = (bf16_t*)nxt((size_t)N * HD * 2);
    bf16_t* p1b = (bf16_t*)nxt((size_t)N * HD * 2);
    bf16_t* p2b = (bf16_t*)nxt((size_t)N * HD * 2);
    bf16_t* p3b = (bf16_t*)nxt((size_t)N * HD * 2);
    bf16_t* knb = (bf16_t*)nxt((size_t)N * HD * 2);
    bf16_t* qnb = (bf16_t*)nxt((size_t)N * HD * 2);
    // fragment-packed bf16 weights
    bf16_t* Wp_in = (bf16_t*)nxt((size_t)8 * 4 * 64 * 8 * 2);
    bf16_t* Wp_q = (bf16_t*)nxt((size_t)2 * 8 * 4 * 64 * 8 * 2);
    bf16_t* Wp_k = (bf16_t*)nxt((size_t)2 * 8 * 4 * 64 * 8 * 2);
    bf16_t* Wp_fc = (bf16_t*)nxt((size_t)2 * 8 * 20 * 64 * 8 * 2);
    bf16_t* WpM1 = (bf16_t*)nxt((size_t)8 * 4 * 64 * 8 * 2);
    bf16_t* Wp_out = (bf16_t*)nxt((size_t)3 * 4 * 64 * 8 * 2);

    const int GB = (N + 63) / 64;
    const int GB2 = (N + 127) / 128;
    const int QSZ = HD * HD;
    const int FSZ = 8 * 20 * 64 * 8;
    const int NB = (N + 255) / 256;

    // ---- CSR build ----
    hipMemsetAsync(counts, 0, (size_t)2 * ((N * 4 + 255) & ~255), stream);
    count_edges<<<(E + 255) / 256, 256, 0, stream>>>(colp, counts, E);
    scan1<<<NB, 256, 0, stream>>>(counts, offsets, bsum, dis, N);
    scan2<<<1, 256, 0, stream>>>(bsum, offsets, NB, N);
    scan3<<<NB, 256, 0, stream>>>(offsets, bsum, N);
    scatter_edges3<<<(E + 255) / 256, 256, 0, stream>>>(rowp, colp, dis, offsets, cursor,
                                                        edges, E);

    // ---- all weight packing + zero BN stats (one launch) ----
    wcvt_all<<<124, 256, 0, stream>>>(W_in, Wq, Wk, Wfc, W_out, Wp_in, Wp_q, Wp_k, Wp_fc,
                                      Wp_out, bnsum, bnsumsq);

    // ---- input layer (fused BN stats) ----
    gemm128s<float, false><<<GB, 256, 0, stream>>>(x, Wp_in, b_in, nullptr, nullptr, bnsum,
                                                   bnsumsq, nullptr, 0, nullptr, zb, N);
    bn_apply2<<<(N * 32 + 255) / 256, 256, 0, stream>>>(zb, hb, bnsum, bnsumsq, bn_g, bn_b,
                                                        N * 32);

    for (int i = 0; i < 2; i++) {
        const float* bq_i = bq + (size_t)i * HD;
        const float* bk_i = bk + (size_t)i * HD;
        const float* bfc_i = bfc + (size_t)i * HD;
        const float* Wfc_i = Wfc + (size_t)i * 640 * HD;  // rows 0..127 = W0
        bf16_t* Wp_q_i = Wp_q + (size_t)i * QSZ;
        bf16_t* Wp_k_i = Wp_k + (size_t)i * QSZ;
        bf16_t* Wp_fc_i = Wp_fc + (size_t)i * FSZ;

        // K-hop diffusion (bf16)
        prop_b3<<<(N + 3) / 4, 256, 0, stream>>>(offsets, edges, hb, p1b);
        prop_b3<<<(N + 3) / 4, 256, 0, stream>>>(offsets, edges, p1b, p2b);
        prop_b3<<<(N + 3) / 4, 256, 0, stream>>>(offsets, edges, p2b, p3b);

        // attention: k-gemm (also zeroes kvs+ksum+vsum), kvs, q-gemm (fused den)
        gemm128s<bf16_t, true><<<GB, 256, 0, stream>>>(hb, Wp_k_i, bk_i, nullptr, nullptr,
                                                       nullptr, nullptr, kvs, HD * HD + 2 * HD,
                                                       nullptr, knb, N);
        kvs_mfma<<<256, 256, 0, stream>>>(knb, hb, kvs, ksum, vsum, N);
        gemm128s<bf16_t, true><<<GB, 256, 0, stream>>>(hb, Wp_q_i, bq_i, ksum, den, nullptr,
                                                       nullptr, nullptr, 0, nullptr, qnb, N);
        m1_pack<<<65, 256, 0, stream>>>(kvs, Wfc_i, vsum, WpM1, bvec, bnsum, bnsumsq);

        // z = qn@M1 + dinv*bvec + [h,p1,p2,p3]@W[128:] + bfc + hb  (fused BN stats)
        gemm_fc<<<GB2, 256, 0, stream>>>(qnb, hb, p1b, p2b, p3b, WpM1, Wp_fc_i, bvec, bfc_i,
                                         den, hb, bnsum, bnsumsq, zb, N);
        bn_apply2<<<(N * 32 + 255) / 256, 256, 0, stream>>>(zb, hb, bnsum, bnsumsq,
                                                            bn_g + (size_t)(i + 1) * HD,
                                                            bn_b + (size_t)(i + 1) * HD,
                                                            N * 32);
    }

    out_mfma<<<GB, 256, 0, stream>>>(hb, Wp_out, b_out, out, N);
}

// Round 13
// 602.816 us; speedup vs baseline: 1.1588x; 1.0143x over previous
//
#include <hip/hip_runtime.h>
#include <hip/hip_bf16.h>
#include <hip/hip_fp16.h>
#include <math.h>

#define NN 50000
#define NE 800000
#define HD 128
#define EPS_BN 1e-5f

typedef __bf16 bf16_t;
typedef bf16_t bf16x8 __attribute__((ext_vector_type(8)));
typedef bf16_t bf16x4 __attribute__((ext_vector_type(4)));
typedef float f32x4 __attribute__((ext_vector_type(4)));

// ---------------- CSR build ----------------
__global__ void count_edges(const int* __restrict__ col, int* __restrict__ counts, int E) {
    int e = blockIdx.x * 256 + threadIdx.x;
    if (e >= E) return;
    atomicAdd(&counts[col[e]], 1);
}

// scan1 + dis fused
__global__ __launch_bounds__(256) void scan1(const int* __restrict__ counts,
                                             int* __restrict__ offsets,
                                             int* __restrict__ bsum,
                                             float* __restrict__ dis, int n) {
    __shared__ int wsl[4];
    int t = threadIdx.x, lane = t & 63, w = t >> 6;
    int i = blockIdx.x * 256 + t;
    int v = (i < n) ? counts[i] : 0;
    if (i < n) dis[i] = (v > 0) ? rsqrtf((float)v) : 0.0f;
    int x = v;
    #pragma unroll
    for (int o = 1; o < 64; o <<= 1) {
        int tt = __shfl_up(x, o, 64);
        if (lane >= o) x += tt;
    }
    if (lane == 63) wsl[w] = x;
    __syncthreads();
    if (t == 0) {
        int s = 0;
        #pragma unroll
        for (int k = 0; k < 4; k++) { int tmp = wsl[k]; wsl[k] = s; s += tmp; }
        bsum[blockIdx.x] = s;
    }
    __syncthreads();
    if (i < n) offsets[i] = x - v + wsl[w];
}

__global__ __launch_bounds__(256) void scan2(int* __restrict__ bsum, int* __restrict__ offsets,
                                             int nb, int n) {
    __shared__ int wsl[4];
    int t = threadIdx.x, lane = t & 63, w = t >> 6;
    int v = (t < nb) ? bsum[t] : 0;
    int x = v;
    #pragma unroll
    for (int o = 1; o < 64; o <<= 1) {
        int tt = __shfl_up(x, o, 64);
        if (lane >= o) x += tt;
    }
    if (lane == 63) wsl[w] = x;
    __syncthreads();
    if (t == 0) {
        int s = 0;
        #pragma unroll
        for (int k = 0; k < 4; k++) { int tmp = wsl[k]; wsl[k] = s; s += tmp; }
    }
    __syncthreads();
    int excl = x - v + wsl[w];
    if (t < nb) bsum[t] = excl;
    if (t == nb - 1) offsets[n] = excl + v;
}

__global__ void scan3(int* __restrict__ offsets, const int* __restrict__ bsum, int n) {
    int i = blockIdx.x * 256 + threadIdx.x;
    if (i < n) offsets[i] += bsum[blockIdx.x];
}

// 4-byte edge record: row (low 16) | fp16 weight (high 16). N=50000 < 65536.
// Non-temporal store: bypass L2 so random-store lines don't ping-pong across XCDs.
__global__ void scatter_edges3(const int* __restrict__ row, const int* __restrict__ col,
                               const float* __restrict__ dis, const int* __restrict__ offsets,
                               int* __restrict__ cursor, unsigned int* __restrict__ edges,
                               int E) {
    int e = blockIdx.x * 256 + threadIdx.x;
    if (e >= E) return;
    int c = col[e], r = row[e];
    int pos = offsets[c] + atomicAdd(&cursor[c], 1);
    unsigned short hw = __half_as_ushort(__float2half(dis[c] * dis[r]));
    unsigned int rec = (unsigned int)r | ((unsigned int)hw << 16);
    __builtin_nontemporal_store(rec, &edges[pos]);
}

// ---------------- Graph propagation: 1 wave/node, 4 quarters, pipelined edge prefetch ----------------
__global__ __launch_bounds__(256) void prop_b3(const int* __restrict__ offsets,
                                               const unsigned int* __restrict__ edges,
                                               const bf16_t* __restrict__ in,
                                               bf16_t* __restrict__ out) {
    int wave = threadIdx.x >> 6;
    int lane = threadIdx.x & 63;
    int q = lane >> 4;          // quarter 0..3
    int ch8 = (lane & 15) * 8;  // 8 channels per lane
    int c = blockIdx.x * 4 + wave;
    if (c >= NN) return;
    int s = offsets[c], e = offsets[c + 1];
    float a[8] = {};
    int i = s + q;
    int last = (e > 0) ? e - 1 : 0;
    // prefetch first pair (clamped; unused values discarded by loop conditions)
    unsigned int n0 = edges[(i < e) ? i : last];
    unsigned int n1 = edges[(i + 4 < e) ? i + 4 : last];
    while (i + 4 < e) {
        unsigned int r0 = n0, r1 = n1;
        int inext = i + 8;
        n0 = edges[(inext < e) ? inext : last];
        n1 = edges[(inext + 4 < e) ? inext + 4 : last];
        bf16x8 v0 = *(const bf16x8*)(in + ((size_t)(r0 & 0xFFFFu) << 7) + ch8);
        bf16x8 v1 = *(const bf16x8*)(in + ((size_t)(r1 & 0xFFFFu) << 7) + ch8);
        float w0 = __half2float(__ushort_as_half((unsigned short)(r0 >> 16)));
        float w1 = __half2float(__ushort_as_half((unsigned short)(r1 >> 16)));
        #pragma unroll
        for (int j = 0; j < 8; j++) a[j] += w0 * (float)v0[j] + w1 * (float)v1[j];
        i = inext;
    }
    if (i < e) {
        bf16x8 v0 = *(const bf16x8*)(in + ((size_t)(n0 & 0xFFFFu) << 7) + ch8);
        float w0 = __half2float(__ushort_as_half((unsigned short)(n0 >> 16)));
        #pragma unroll
        for (int j = 0; j < 8; j++) a[j] += w0 * (float)v0[j];
    }
    #pragma unroll
    for (int j = 0; j < 8; j++) {
        a[j] += __shfl_xor(a[j], 16);
        a[j] += __shfl_xor(a[j], 32);
    }
    if (q == 0) {
        bf16x8 o;
        #pragma unroll
        for (int j = 0; j < 8; j++) o[j] = (bf16_t)a[j];
        *(bf16x8*)(out + ((size_t)c << 7) + ch8) = o;
    }
}

// ---------------- Mega weight-pack kernel ----------------
__device__ inline void pack_frag(const float* __restrict__ W, bf16_t* __restrict__ Wp, int nkc,
                                 int lb) {
    int p = lb * 256 + threadIdx.x;
    if (p >= 8 * nkc * 64) return;
    int lane = p & 63;
    int tk = p >> 6;
    int kc = tk % nkc;
    int t = tk / nkc;
    int n = t * 16 + (lane & 15);
    int k0 = kc * 32 + (lane >> 4) * 8;
    bf16x8 f;
    #pragma unroll
    for (int j = 0; j < 8; j++) f[j] = (bf16_t)W[(size_t)(k0 + j) * 128 + n];
    *(bf16x8*)(Wp + (size_t)p * 8) = f;
}

__global__ void wcvt_all(const float* __restrict__ W_in, const float* __restrict__ Wq,
                         const float* __restrict__ Wk, const float* __restrict__ Wfc,
                         const float* __restrict__ W_out, bf16_t* __restrict__ Wp_in,
                         bf16_t* __restrict__ Wp_q, bf16_t* __restrict__ Wp_k,
                         bf16_t* __restrict__ Wp_fc, bf16_t* __restrict__ Wp_out,
                         float* __restrict__ bnsum, float* __restrict__ bnsumsq) {
    const int QSZ = HD * HD;
    const int FSZ = 8 * 20 * 64 * 8;
    int b = blockIdx.x;
    if (b < 8) { pack_frag(W_in, Wp_in, 4, b); return; }
    if (b < 16) { pack_frag(Wq, Wp_q, 4, b - 8); return; }
    if (b < 24) { pack_frag(Wq + QSZ, Wp_q + QSZ, 4, b - 16); return; }
    if (b < 32) { pack_frag(Wk, Wp_k, 4, b - 24); return; }
    if (b < 40) { pack_frag(Wk + QSZ, Wp_k + QSZ, 4, b - 32); return; }
    if (b < 80) { pack_frag(Wfc, Wp_fc, 20, b - 40); return; }
    if (b < 120) { pack_frag(Wfc + 640 * HD, Wp_fc + FSZ, 20, b - 80); return; }
    if (b < 123) {  // W_out [128][40] -> 3 tiles padded to 48
        int p = (b - 120) * 256 + threadIdx.x;
        if (p >= 3 * 4 * 64) return;
        int lane = p & 63;
        int tk = p >> 6;
        int kc = tk & 3;
        int t = tk >> 2;
        int n = t * 16 + (lane & 15);
        int k0 = kc * 32 + (lane >> 4) * 8;
        bf16x8 f;
        #pragma unroll
        for (int j = 0; j < 8; j++)
            f[j] = (n < 40) ? (bf16_t)W_out[(size_t)(k0 + j) * 40 + n] : (bf16_t)0.0f;
        *(bf16x8*)(Wp_out + (size_t)p * 8) = f;
        return;
    }
    int t = threadIdx.x;
    if (t < 128) bnsum[t] = 0.0f;
    else bnsumsq[t - 128] = 0.0f;
}

// ---------------- A-fragment loaders ----------------
__device__ inline bf16x8 loadA(const float* ap) {
    float4 a0 = *(const float4*)ap;
    float4 a1 = *(const float4*)(ap + 4);
    bf16x8 f;
    f[0] = (bf16_t)a0.x; f[1] = (bf16_t)a0.y; f[2] = (bf16_t)a0.z; f[3] = (bf16_t)a0.w;
    f[4] = (bf16_t)a1.x; f[5] = (bf16_t)a1.y; f[6] = (bf16_t)a1.z; f[7] = (bf16_t)a1.w;
    return f;
}
__device__ inline bf16x8 loadA(const bf16_t* ap) { return *(const bf16x8*)ap; }

// ---------------- MFMA GEMM (K=128): 2 m-tiles/wave, batched A; norm / den / bn-stats / zero ----------------
template <typename T, bool NORM>
__global__ __launch_bounds__(256, 1) void gemm128s(const T* __restrict__ A,
                                                   const bf16_t* __restrict__ Wp,
                                                   const float* __restrict__ bias,
                                                   const float* __restrict__ ksum_p,
                                                   float* __restrict__ den_out,
                                                   float* __restrict__ sums,
                                                   float* __restrict__ sumsq,
                                                   float* __restrict__ zero_buf, int zero_len,
                                                   float* __restrict__ out,
                                                   bf16_t* __restrict__ outb, int N) {
    __shared__ float lsum[128], lsq[128];
    int tid = threadIdx.x;
    if (zero_buf && blockIdx.x < 17) {  // zero kvs+ksum+vsum for the next kernel
        int base = (blockIdx.x * 256 + tid) * 4;
        if (base < zero_len) *(float4*)(zero_buf + base) = make_float4(0.f, 0.f, 0.f, 0.f);
    }
    int wave = tid >> 6;
    int lane = tid & 63;
    int quad = lane >> 4;
    int l16 = lane & 15;
    int m0 = blockIdx.x * 128 + wave * 32;  // 2 m-tiles per wave

    bf16x8 afr[2][4];
    #pragma unroll
    for (int m = 0; m < 2; m++) {
        int arow = m0 + m * 16 + l16;
        if (arow < N) {
            #pragma unroll
            for (int kc = 0; kc < 4; kc++)
                afr[m][kc] = loadA(A + ((size_t)arow << 7) + kc * 32 + quad * 8);
        } else {
            #pragma unroll
            for (int kc = 0; kc < 4; kc++) afr[m][kc] = (bf16x8){};
        }
    }

    f32x4 acc[2][8] = {};
    #pragma unroll
    for (int kc = 0; kc < 4; kc++) {
        bf16x8 bfr[8];
        #pragma unroll
        for (int t = 0; t < 8; t++)
            bfr[t] = *(const bf16x8*)(Wp + (size_t)(((t * 4 + kc) * 64) + lane) * 8);
        #pragma unroll
        for (int t = 0; t < 8; t++)
            #pragma unroll
            for (int m = 0; m < 2; m++)
                acc[m][t] = __builtin_amdgcn_mfma_f32_16x16x32_bf16(afr[m][kc], bfr[t],
                                                                    acc[m][t], 0, 0, 0);
    }
    // epilogue (in place on acc)
    #pragma unroll
    for (int m = 0; m < 2; m++) {
        #pragma unroll
        for (int t = 0; t < 8; t++) {
            float b = bias ? bias[t * 16 + l16] : 0.0f;
            #pragma unroll
            for (int r = 0; r < 4; r++) acc[m][t][r] += b;
        }
        if (NORM) {
            #pragma unroll
            for (int r = 0; r < 4; r++) {
                float p = 0.0f;
                #pragma unroll
                for (int t = 0; t < 8; t++) p += acc[m][t][r] * acc[m][t][r];
                p += __shfl_xor(p, 1);
                p += __shfl_xor(p, 2);
                p += __shfl_xor(p, 4);
                p += __shfl_xor(p, 8);
                float inv = rsqrtf(p);
                #pragma unroll
                for (int t = 0; t < 8; t++) acc[m][t][r] *= inv;
            }
        }
        if (ksum_p) {  // fused den = qn . ksum + N; scale row by 1/den
            float kv[8];
            #pragma unroll
            for (int t = 0; t < 8; t++) kv[t] = ksum_p[t * 16 + l16];
            #pragma unroll
            for (int r = 0; r < 4; r++) {
                float dp = 0.0f;
                #pragma unroll
                for (int t = 0; t < 8; t++) dp += acc[m][t][r] * kv[t];
                dp += __shfl_xor(dp, 1);
                dp += __shfl_xor(dp, 2);
                dp += __shfl_xor(dp, 4);
                dp += __shfl_xor(dp, 8);
                float dv = dp + (float)NN;
                int rr = m0 + m * 16 + quad * 4 + r;
                if (l16 == 0 && rr < N) den_out[rr] = dv;
                float dinv = 1.0f / dv;
                #pragma unroll
                for (int t = 0; t < 8; t++) acc[m][t][r] *= dinv;
            }
        }
        #pragma unroll
        for (int r = 0; r < 4; r++) {
            int rr = m0 + m * 16 + quad * 4 + r;
            if (rr >= N) continue;
            #pragma unroll
            for (int t = 0; t < 8; t++) {
                int c = t * 16 + l16;
                float v = acc[m][t][r];
                if (out) out[((size_t)rr << 7) + c] = v;
                if (outb) outb[((size_t)rr << 7) + c] = (bf16_t)v;
            }
        }
    }
    if (sums) {  // fused BN stats over both m-tiles
        if (tid < 128) { lsum[tid] = 0.0f; lsq[tid] = 0.0f; }
        __syncthreads();
        float sp[8] = {}, qp[8] = {};
        #pragma unroll
        for (int m = 0; m < 2; m++)
            #pragma unroll
            for (int r = 0; r < 4; r++) {
                int rr = m0 + m * 16 + quad * 4 + r;
                if (rr >= N) continue;
                #pragma unroll
                for (int t = 0; t < 8; t++) {
                    float v = acc[m][t][r];
                    sp[t] += v;
                    qp[t] += v * v;
                }
            }
        #pragma unroll
        for (int t = 0; t < 8; t++) {
            sp[t] += __shfl_xor(sp[t], 16);
            sp[t] += __shfl_xor(sp[t], 32);
            qp[t] += __shfl_xor(qp[t], 16);
            qp[t] += __shfl_xor(qp[t], 32);
        }
        if (quad == 0) {
            #pragma unroll
            for (int t = 0; t < 8; t++) {
                atomicAdd(&lsum[t * 16 + l16], sp[t]);
                atomicAdd(&lsq[t * 16 + l16], qp[t]);
            }
        }
        __syncthreads();
        if (tid < 128) {
            atomicAdd(&sums[tid], lsum[tid]);
            atomicAdd(&sumsq[tid], lsq[tid]);
        }
    }
}

// ---------------- fc GEMM: single 640-K loop, 2 m-tiles/wave, fused BN stats ----------------
__global__ __launch_bounds__(256, 1) void gemm_fc(
    const bf16_t* __restrict__ qn, const bf16_t* __restrict__ s1, const bf16_t* __restrict__ s2,
    const bf16_t* __restrict__ s3, const bf16_t* __restrict__ s4,
    const bf16_t* __restrict__ WpM1, const bf16_t* __restrict__ Wp,
    const float* __restrict__ bvec, const float* __restrict__ bfc,
    const float* __restrict__ den, const bf16_t* __restrict__ resb,
    float* __restrict__ sums, float* __restrict__ sumsq,
    bf16_t* __restrict__ outb, int N) {
    __shared__ float lsum[128], lsq[128];
    const bf16_t* srcs[5] = {qn, s1, s2, s3, s4};
    int tid = threadIdx.x;
    int wave = tid >> 6;
    int lane = tid & 63;
    int quad = lane >> 4;
    int l16 = lane & 15;
    int m0 = blockIdx.x * 128 + wave * 32;  // 2 m-tiles per wave

    f32x4 acc[2][8] = {};
    #pragma unroll
    for (int kc = 0; kc < 20; kc++) {
        int s = kc >> 2;
        int klocal = (kc & 3) * 32;
        bf16x8 bfr[8];
        #pragma unroll
        for (int t = 0; t < 8; t++) {
            const bf16_t* bp = (kc < 4) ? WpM1 + (size_t)(((t * 4 + kc) * 64) + lane) * 8
                                        : Wp + (size_t)(((t * 20 + kc) * 64) + lane) * 8;
            bfr[t] = *(const bf16x8*)bp;
        }
        bf16x8 af[2] = {};
        #pragma unroll
        for (int m = 0; m < 2; m++) {
            int arow = m0 + m * 16 + l16;
            if (arow < N)
                af[m] = *(const bf16x8*)(srcs[s] + ((size_t)arow << 7) + klocal + quad * 8);
        }
        #pragma unroll
        for (int t = 0; t < 8; t++) {
            #pragma unroll
            for (int m = 0; m < 2; m++)
                acc[m][t] = __builtin_amdgcn_mfma_f32_16x16x32_bf16(af[m], bfr[t], acc[m][t],
                                                                    0, 0, 0);
        }
    }
    float bv[8], bf[8];
    #pragma unroll
    for (int t = 0; t < 8; t++) {
        bv[t] = bvec[t * 16 + l16];
        bf[t] = bfc[t * 16 + l16];
    }
    if (tid < 128) { lsum[tid] = 0.0f; lsq[tid] = 0.0f; }
    __syncthreads();
    float sp[8] = {}, qp[8] = {};
    #pragma unroll
    for (int m = 0; m < 2; m++) {
        #pragma unroll
        for (int r = 0; r < 4; r++) {
            int rr = m0 + m * 16 + quad * 4 + r;
            if (rr >= N) continue;
            float dinv = 1.0f / den[rr];
            #pragma unroll
            for (int t = 0; t < 8; t++) {
                int c = t * 16 + l16;
                float v = acc[m][t][r] + dinv * bv[t] + bf[t] +
                          (float)resb[((size_t)rr << 7) + c];
                outb[((size_t)rr << 7) + c] = (bf16_t)v;
                sp[t] += v;
                qp[t] += v * v;
            }
        }
    }
    #pragma unroll
    for (int t = 0; t < 8; t++) {
        sp[t] += __shfl_xor(sp[t], 16);
        sp[t] += __shfl_xor(sp[t], 32);
        qp[t] += __shfl_xor(qp[t], 16);
        qp[t] += __shfl_xor(qp[t], 32);
    }
    if (quad == 0) {
        #pragma unroll
        for (int t = 0; t < 8; t++) {
            atomicAdd(&lsum[t * 16 + l16], sp[t]);
            atomicAdd(&lsq[t * 16 + l16], qp[t]);
        }
    }
    __syncthreads();
    if (tid < 128) {
        atomicAdd(&sums[tid], lsum[tid]);
        atomicAdd(&sumsq[tid], lsq[tid]);
    }
}

// ---------------- out GEMM via MFMA ----------------
__global__ __launch_bounds__(256) void out_mfma(const bf16_t* __restrict__ hb,
                                                const bf16_t* __restrict__ Wp,
                                                const float* __restrict__ bias,
                                                float* __restrict__ out, int N) {
    int wave = threadIdx.x >> 6;
    int lane = threadIdx.x & 63;
    int quad = lane >> 4;
    int l16 = lane & 15;
    int m0 = blockIdx.x * 64 + wave * 16;
    int arow = m0 + l16;

    bf16x8 afr[4];
    if (arow < N) {
        #pragma unroll
        for (int kc = 0; kc < 4; kc++)
            afr[kc] = *(const bf16x8*)(hb + ((size_t)arow << 7) + kc * 32 + quad * 8);
    } else {
        #pragma unroll
        for (int kc = 0; kc < 4; kc++) afr[kc] = (bf16x8){};
    }
    f32x4 acc[3] = {};
    #pragma unroll
    for (int kc = 0; kc < 4; kc++) {
        #pragma unroll
        for (int t = 0; t < 3; t++) {
            const bf16_t* bp = Wp + (size_t)(((t * 4 + kc) * 64) + lane) * 8;
            acc[t] = __builtin_amdgcn_mfma_f32_16x16x32_bf16(afr[kc], *(const bf16x8*)bp,
                                                             acc[t], 0, 0, 0);
        }
    }
    #pragma unroll
    for (int r = 0; r < 4; r++) {
        int rr = m0 + quad * 4 + r;
        if (rr >= N) continue;
        #pragma unroll
        for (int t = 0; t < 3; t++) {
            int c = t * 16 + l16;
            if (c < 40) out[(size_t)rr * 40 + c] = acc[t][r] + bias[c];
        }
    }
}

// ---------------- kvs via MFMA ----------------
__global__ __launch_bounds__(256) void kvs_mfma(const bf16_t* __restrict__ kn,
                                                const bf16_t* __restrict__ v,
                                                float* __restrict__ kvs,
                                                float* __restrict__ ksum,
                                                float* __restrict__ vsum, int N) {
    __shared__ bf16_t Lk[32][132];
    __shared__ bf16_t Lv[32][132];
    __shared__ float lred[256];
    int t = threadIdx.x;
    int wave = t >> 6, lane = t & 63, quad = lane >> 4, l16 = lane & 15;
    int tr = t >> 4, tc = (t & 15) * 8;
    int mbase = wave * 32;
    f32x4 acc[2][8] = {};
    float ks[8] = {}, vs[8] = {};
    for (int base = blockIdx.x * 32; base < N; base += gridDim.x * 32) {
        __syncthreads();
        #pragma unroll
        for (int hh = 0; hh < 2; hh++) {
            int r = hh * 16 + tr;
            int rowi = base + r;
            bf16x8 ck = {}, cv = {};
            if (rowi < N) {
                ck = *(const bf16x8*)(kn + ((size_t)rowi << 7) + tc);
                cv = *(const bf16x8*)(v + ((size_t)rowi << 7) + tc);
            }
            bf16x4 klo, khi, vlo, vhi;
            #pragma unroll
            for (int j = 0; j < 4; j++) {
                klo[j] = ck[j]; khi[j] = ck[j + 4];
                vlo[j] = cv[j]; vhi[j] = cv[j + 4];
                ks[j] += (float)ck[j]; ks[j + 4] += (float)ck[j + 4];
                vs[j] += (float)cv[j]; vs[j + 4] += (float)cv[j + 4];
            }
            *(bf16x4*)&Lk[r][tc] = klo;
            *(bf16x4*)&Lk[r][tc + 4] = khi;
            *(bf16x4*)&Lv[r][tc] = vlo;
            *(bf16x4*)&Lv[r][tc + 4] = vhi;
        }
        __syncthreads();
        bf16x8 af[2], bfr[8];
        #pragma unroll
        for (int mt = 0; mt < 2; mt++)
            #pragma unroll
            for (int j = 0; j < 8; j++) af[mt][j] = Lk[quad * 8 + j][mbase + mt * 16 + l16];
        #pragma unroll
        for (int tt = 0; tt < 8; tt++)
            #pragma unroll
            for (int j = 0; j < 8; j++) bfr[tt][j] = Lv[quad * 8 + j][tt * 16 + l16];
        #pragma unroll
        for (int mt = 0; mt < 2; mt++)
            #pragma unroll
            for (int tt = 0; tt < 8; tt++)
                acc[mt][tt] = __builtin_amdgcn_mfma_f32_16x16x32_bf16(af[mt], bfr[tt],
                                                                      acc[mt][tt], 0, 0, 0);
    }
    #pragma unroll
    for (int mt = 0; mt < 2; mt++)
        #pragma unroll
        for (int tt = 0; tt < 8; tt++)
            #pragma unroll
            for (int r = 0; r < 4; r++) {
                int m = mbase + mt * 16 + quad * 4 + r;
                int d = tt * 16 + l16;
                atomicAdd(&kvs[m * HD + d], acc[mt][tt][r]);
            }
    lred[t] = 0.0f;
    __syncthreads();
    #pragma unroll
    for (int j = 0; j < 8; j++) {
        atomicAdd(&lred[tc + j], ks[j]);
        atomicAdd(&lred[128 + tc + j], vs[j]);
    }
    __syncthreads();
    if (t < 128) {
        atomicAdd(&ksum[t], lred[t]);
        atomicAdd(&vsum[t], lred[t + 128]);
    }
}

// ---------------- M1 = kvs @ W0 (frag-packed), bvec = vsum @ W0, zero BN stats ----------------
__global__ void m1_pack(const float* __restrict__ kvs, const float* __restrict__ W0,
                        const float* __restrict__ vsum, bf16_t* __restrict__ WpM1,
                        float* __restrict__ bvec, float* __restrict__ bnsum,
                        float* __restrict__ bnsumsq) {
    if (blockIdx.x == 64) {
        int t = threadIdx.x;
        if (t < 128) {
            bnsum[t] = 0.0f;
            float acc = 0.0f;
            for (int d = 0; d < 128; d++) acc += vsum[d] * W0[d * 128 + t];
            bvec[t] = acc;
        } else {
            bnsumsq[t - 128] = 0.0f;
        }
        return;
    }
    int idx = blockIdx.x * 256 + threadIdx.x;
    int m = idx >> 7;
    int c = idx & 127;
    float acc = 0.0f;
    for (int d = 0; d < 128; d += 4) {
        float4 k4 = *(const float4*)(kvs + m * 128 + d);
        acc += k4.x * W0[(d + 0) * 128 + c] + k4.y * W0[(d + 1) * 128 + c] +
               k4.z * W0[(d + 2) * 128 + c] + k4.w * W0[(d + 3) * 128 + c];
    }
    int t = c >> 4, l16 = c & 15, kc = m >> 5, quad = (m >> 3) & 3, j = m & 7;
    int lane = quad * 16 + l16;
    WpM1[(size_t)(((t * 4 + kc) * 64) + lane) * 8 + j] = (bf16_t)acc;
}

// ---------------- BN apply (finalize fused per block) ----------------
__global__ void bn_apply2(const bf16_t* __restrict__ z, bf16_t* __restrict__ hb,
                          const float* __restrict__ sums, const float* __restrict__ sumsq,
                          const float* __restrict__ g, const float* __restrict__ bb, int n4) {
    __shared__ float sc[128], sh[128];
    int t = threadIdx.x;
    if (t < 128) {
        float m = sums[t] / (float)NN;
        float var = sumsq[t] / (float)NN - m * m;
        float s = g[t] * rsqrtf(var + EPS_BN);
        sc[t] = s;
        sh[t] = bb[t] - m * s;
    }
    __syncthreads();
    int i = blockIdx.x * 256 + t;
    if (i >= n4) return;
    int c4 = (i & 31) * 4;
    bf16x4 zv = *(const bf16x4*)(z + (size_t)i * 4);
    bf16x4 o;
    #pragma unroll
    for (int j = 0; j < 4; j++)
        o[j] = (bf16_t)fmaxf((float)zv[j] * sc[c4 + j] + sh[c4 + j], 0.0f);
    *(bf16x4*)(hb + (size_t)i * 4) = o;
}

extern "C" void kernel_launch(void* const* d_in, const int* in_sizes, int n_in,
                              void* d_out, int out_size, void* d_ws, size_t ws_size,
                              hipStream_t stream) {
    const float* x = (const float*)d_in[0];
    const int* eidx = (const int*)d_in[1];
    const float* W_in = (const float*)d_in[2];
    const float* b_in = (const float*)d_in[3];
    const float* Wq = (const float*)d_in[4];
    const float* bq = (const float*)d_in[5];
    const float* Wk = (const float*)d_in[6];
    const float* bk = (const float*)d_in[7];
    const float* Wfc = (const float*)d_in[8];
    const float* bfc = (const float*)d_in[9];
    const float* W_out = (const float*)d_in[10];
    const float* b_out = (const float*)d_in[11];
    const float* bn_g = (const float*)d_in[12];
    const float* bn_b = (const float*)d_in[13];
    float* out = (float*)d_out;

    const int N = NN, E = NE;
    const int* rowp = eidx;
    const int* colp = eidx + E;

    char* ws = (char*)d_ws;
    size_t off = 0;
    auto nxt = [&](size_t bytes) -> void* {
        void* p = ws + off;
        off += (bytes + 255) & ~(size_t)255;
        return p;
    };
    int* counts = (int*)nxt((size_t)N * 4);
    int* cursor = (int*)nxt((size_t)N * 4);  // adjacent to counts: one memset covers both
    int* offsets = (int*)nxt((size_t)(N + 1) * 4);
    int* bsum = (int*)nxt(1024);
    unsigned int* edges = (unsigned int*)nxt((size_t)E * 4);
    float* dis = (float*)nxt((size_t)N * 4);
    float* den = (float*)nxt((size_t)N * 4);
    float* kvs = (float*)nxt((size_t)HD * HD * 4);  // + ksum + vsum contiguous
    float* ksum = (float*)nxt((size_t)HD * 4);
    float* vsum = (float*)nxt((size_t)HD * 4);
    float* bnsum = (float*)nxt((size_t)HD * 4);
    float* bnsumsq = (float*)nxt((size_t)HD * 4);
    float* bvec = (float*)nxt((size_t)HD * 4);
    // bf16 activations
    bf16_t* zb = (bf16_t*)nxt((size_t)N * HD * 2);
    bf16_t* hb = (bf16_t*)nxt((size_t)N * HD * 2);
    bf16_t* p1b = (bf16_t*)nxt((size_t)N * HD * 2);
    bf16_t* p2b = (bf16_t*)nxt((size_t)N * HD * 2);
    bf16_t* p3b = (bf16_t*)nxt((size_t)N * HD * 2);
    bf16_t* knb = (bf16_t*)nxt((size_t)N * HD * 2);
    bf16_t* qnb = (bf16_t*)nxt((size_t)N * HD * 2);
    // fragment-packed bf16 weights
    bf16_t* Wp_in = (bf16_t*)nxt((size_t)8 * 4 * 64 * 8 * 2);
    bf16_t* Wp_q = (bf16_t*)nxt((size_t)2 * 8 * 4 * 64 * 8 * 2);
    bf16_t* Wp_k = (bf16_t*)nxt((size_t)2 * 8 * 4 * 64 * 8 * 2);
    bf16_t* Wp_fc = (bf16_t*)nxt((size_t)2 * 8 * 20 * 64 * 8 * 2);
    bf16_t* WpM1 = (bf16_t*)nxt((size_t)8 * 4 * 64 * 8 * 2);
    bf16_t* Wp_out = (bf16_t*)nxt((size_t)3 * 4 * 64 * 8 * 2);

    const int GB = (N + 63) / 64;
    const int GB2 = (N + 127) / 128;
    const int QSZ = HD * HD;
    const int FSZ = 8 * 20 * 64 * 8;
    const int NB = (N + 255) / 256;

    // ---- CSR build ----
    hipMemsetAsync(counts, 0, (size_t)2 * ((N * 4 + 255) & ~255), stream);
    count_edges<<<(E + 255) / 256, 256, 0, stream>>>(colp, counts, E);
    scan1<<<NB, 256, 0, stream>>>(counts, offsets, bsum, dis, N);
    scan2<<<1, 256, 0, stream>>>(bsum, offsets, NB, N);
    scan3<<<NB, 256, 0, stream>>>(offsets, bsum, N);
    scatter_edges3<<<(E + 255) / 256, 256, 0, stream>>>(rowp, colp, dis, offsets, cursor,
                                                        edges, E);

    // ---- all weight packing + zero BN stats (one launch) ----
    wcvt_all<<<124, 256, 0, stream>>>(W_in, Wq, Wk, Wfc, W_out, Wp_in, Wp_q, Wp_k, Wp_fc,
                                      Wp_out, bnsum, bnsumsq);

    // ---- input layer (fused BN stats) ----
    gemm128s<float, false><<<GB2, 256, 0, stream>>>(x, Wp_in, b_in, nullptr, nullptr, bnsum,
                                                    bnsumsq, nullptr, 0, nullptr, zb, N);
    bn_apply2<<<(N * 32 + 255) / 256, 256, 0, stream>>>(zb, hb, bnsum, bnsumsq, bn_g, bn_b,
                                                        N * 32);

    for (int i = 0; i < 2; i++) {
        const float* bq_i = bq + (size_t)i * HD;
        const float* bk_i = bk + (size_t)i * HD;
        const float* bfc_i = bfc + (size_t)i * HD;
        const float* Wfc_i = Wfc + (size_t)i * 640 * HD;  // rows 0..127 = W0
        bf16_t* Wp_q_i = Wp_q + (size_t)i * QSZ;
        bf16_t* Wp_k_i = Wp_k + (size_t)i * QSZ;
        bf16_t* Wp_fc_i = Wp_fc + (size_t)i * FSZ;

        // K-hop diffusion (bf16)
        prop_b3<<<(N + 3) / 4, 256, 0, stream>>>(offsets, edges, hb, p1b);
        prop_b3<<<(N + 3) / 4, 256, 0, stream>>>(offsets, edges, p1b, p2b);
        prop_b3<<<(N + 3) / 4, 256, 0, stream>>>(offsets, edges, p2b, p3b);

        // attention: k-gemm (also zeroes kvs+ksum+vsum), kvs, q-gemm (fused den)
        gemm128s<bf16_t, true><<<GB2, 256, 0, stream>>>(hb, Wp_k_i, bk_i, nullptr, nullptr,
                                                        nullptr, nullptr, kvs,
                                                        HD * HD + 2 * HD, nullptr, knb, N);
        kvs_mfma<<<256, 256, 0, stream>>>(knb, hb, kvs, ksum, vsum, N);
        gemm128s<bf16_t, true><<<GB2, 256, 0, stream>>>(hb, Wp_q_i, bq_i, ksum, den, nullptr,
                                                        nullptr, nullptr, 0, nullptr, qnb, N);
        m1_pack<<<65, 256, 0, stream>>>(kvs, Wfc_i, vsum, WpM1, bvec, bnsum, bnsumsq);

        // z = qn@M1 + dinv*bvec + [h,p1,p2,p3]@W[128:] + bfc + hb  (fused BN stats)
        gemm_fc<<<GB2, 256, 0, stream>>>(qnb, hb, p1b, p2b, p3b, WpM1, Wp_fc_i, bvec, bfc_i,
                                         den, hb, bnsum, bnsumsq, zb, N);
        bn_apply2<<<(N * 32 + 255) / 256, 256, 0, stream>>>(zb, hb, bnsum, bnsumsq,
                                                            bn_g + (size_t)(i + 1) * HD,
                                                            bn_b + (size_t)(i + 1) * HD,
                                                            N * 32);
    }

    out_mfma<<<GB, 256, 0, stream>>>(hb, Wp_out, b_out, out, N);
}